// Round 1
// baseline (610.792 us; speedup 1.0000x reference)
//
#include <hip/hip_runtime.h>
#include <math.h>

#define NB 4
#define NH 512
#define NW 512
#define NC 19
#define NPIX (NB*NH*NW)
#define TS 16
#define NLAD 128
#define INF6 1.0e6f
#define MAXDIS 1.0e5f
#define NPART ((NW/TS)*(NH/TS)*NB)

// ---------------------------------------------------------------------------
// Stage 1: gt -> boundary -> vertical distance scan (Meijster phase 1), G^2
// one thread per (batch, column); exact f32 replication of the jax scan
// ---------------------------------------------------------------------------
__global__ void scan_kernel(const int* __restrict__ tgt, float* __restrict__ g2,
                            unsigned int* __restrict__ flags) {
    int cidx = blockIdx.x * blockDim.x + threadIdx.x;
    if (cidx >= NB * NW) return;
    int b = cidx / NW, j = cidx % NW;
    const int* t = tgt + (size_t)b * NH * NW;
    float* g = g2 + (size_t)b * NH * NW;
    unsigned int bits[NH / 32];
#pragma unroll
    for (int w = 0; w < NH / 32; ++w) bits[w] = 0u;
    float carry = INF6;
    int cur = t[j];
    unsigned int any = 0u;
    for (int i = 0; i < NH; ++i) {
        int nxt = (i + 1 < NH) ? t[(size_t)(i + 1) * NW + j] : cur;
        bool bnd = (cur == 255);
        if (i + 1 < NH && nxt != cur) bnd = true;
        if (j + 1 < NW && t[(size_t)i * NW + j + 1] != cur) bnd = true;
        if (bnd) { bits[i >> 5] |= 1u << (i & 31); any = 1u; }
        carry = fminf(bnd ? 0.f : INF6, carry + 1.f);
        g[(size_t)i * NW + j] = carry;
        cur = nxt;
    }
    float c2 = INF6;
    for (int i = NH - 1; i >= 0; --i) {
        bool bnd = (bits[i >> 5] >> (i & 31)) & 1u;
        c2 = fminf(bnd ? 0.f : INF6, c2 + 1.f);
        float gg = fminf(g[(size_t)i * NW + j], c2);
        g[(size_t)i * NW + j] = gg * gg;
    }
    if (any) atomicOr(&flags[b], 1u);
}

// ---------------------------------------------------------------------------
// Stage 2: row-wise D2 = min_j' (G2[j'] + (j-j')^2), expanding-window search
// then dist = max(sqrt(D2)-1, 0) * any_b. Overwrites g2 in place.
// ---------------------------------------------------------------------------
__global__ __launch_bounds__(256) void rowmin_kernel(float* __restrict__ g2,
                                                     const unsigned int* __restrict__ flags) {
    int row = blockIdx.x;              // b*NH + i
    int b = row / NH;
    float* g = g2 + (size_t)row * NW;
    __shared__ float s[NW];
    for (int j = threadIdx.x; j < NW; j += blockDim.x) s[j] = g[j];
    __syncthreads();
    bool has = flags[b] != 0u;
    for (int j = threadIdx.x; j < NW; j += blockDim.x) {
        float best = s[j];                       // jp == j term (off = 0)
        for (int r = 1; r < NW; ++r) {
            float rr = (float)(r * r);
            if (rr >= best) break;               // no farther jp can improve
            int jl = j - r, jr = j + r;
            if (jl >= 0) best = fminf(best, s[jl] + rr);
            if (jr < NW) best = fminf(best, s[jr] + rr);
        }
        g[j] = has ? fmaxf(sqrtf(best) - 1.f, 0.f) : 0.f;
    }
}

// ---------------------------------------------------------------------------
// Stage 3: kl = KL(P_ij||P_{i+1,j}) + KL(P_ij||P_{i,j+1})  (padded terms = 0)
// LDS-tiled 16x16 with bottom/right halo.
// ---------------------------------------------------------------------------
__global__ __launch_bounds__(256) void kl_kernel(const float* __restrict__ logits,
                                                 float* __restrict__ klb) {
    __shared__ float L[(TS + 1) * (TS + 1) * NC];   // 17*17*19 floats
    __shared__ float M[(TS + 1) * (TS + 1)];
    const int tid = threadIdx.x;
    const int b = blockIdx.z, i0 = blockIdx.y * TS, j0 = blockIdx.x * TS;
    const float* base = logits + ((size_t)b * NH * NW) * NC;
    const int lim = min((TS + 1) * NC, (NW - j0) * NC);
    for (int rr = 0; rr < TS + 1; ++rr) {
        const int gi = i0 + rr;
        if (gi < NH) {
            const float* src = base + ((size_t)gi * NW + j0) * NC;
            for (int t = tid; t < (TS + 1) * NC; t += 256)
                L[rr * (TS + 1) * NC + t] = (t < lim) ? src[t] : 0.f;
        } else {
            for (int t = tid; t < (TS + 1) * NC; t += 256)
                L[rr * (TS + 1) * NC + t] = 0.f;
        }
    }
    __syncthreads();
    for (int p = tid; p < (TS + 1) * (TS + 1); p += 256) {
        const float* v = &L[p * NC];
        float mx = v[0];
#pragma unroll
        for (int c = 1; c < NC; ++c) mx = fmaxf(mx, v[c]);
        float se = 0.f;
#pragma unroll
        for (int c = 0; c < NC; ++c) se += expf(v[c] - mx);
        M[p] = mx + logf(se);                    // logsumexp
    }
    __syncthreads();
    const int tx = tid & (TS - 1), ty = tid >> 4;
    const int gi = i0 + ty, gj = j0 + tx;
    const int p = ty * (TS + 1) + tx;
    const float* lc = &L[p * NC];
    const float mc = M[p];
    float pc[NC];
    float negH = 0.f;
#pragma unroll
    for (int c = 0; c < NC; ++c) {
        float s = lc[c] - mc;
        float e = expf(s);
        pc[c] = e;
        negH += e * s;
    }
    float kl = 0.f;
    if (gi < NH - 1) {
        const float* ln = &L[(p + TS + 1) * NC];
        float dot = 0.f;
#pragma unroll
        for (int c = 0; c < NC; ++c) dot += pc[c] * ln[c];
        kl += negH + M[p + TS + 1] - dot;
    }
    if (gj < NW - 1) {
        const float* ln = &L[(p + 1) * NC];
        float dot = 0.f;
#pragma unroll
        for (int c = 0; c < NC; ++c) dot += pc[c] * ln[c];
        kl += negH + M[p + 1] - dot;
    }
    klb[((size_t)b * NH + gi) * NW + gj] = kl;
}

// ---------------------------------------------------------------------------
// Stage 4: histogram of kl against the exact eps ladder (e = 1e-5; e *= 1.2f)
// bin = first ladder level k with kl <= lad[k]  (so kl > lad[k] <=> bin > k)
// ---------------------------------------------------------------------------
__global__ __launch_bounds__(256) void hist_kernel(const float* __restrict__ klb,
                                                   unsigned int* __restrict__ hist) {
    __shared__ float lad[NLAD];
    __shared__ unsigned int lh[NLAD + 1];
    if (threadIdx.x == 0) {
        float e = 1e-5f;
        for (int k = 0; k < NLAD; ++k) { lad[k] = e; e *= 1.2f; }
    }
    for (int k = threadIdx.x; k < NLAD + 1; k += blockDim.x) lh[k] = 0u;
    __syncthreads();
    for (size_t idx = (size_t)blockIdx.x * blockDim.x + threadIdx.x; idx < NPIX;
         idx += (size_t)gridDim.x * blockDim.x) {
        float v = klb[idx];
        int lo = 0, hi = NLAD;
        while (lo < hi) { int mid = (lo + hi) >> 1; if (v > lad[mid]) lo = mid + 1; else hi = mid; }
        atomicAdd(&lh[lo], 1u);
    }
    __syncthreads();
    for (int k = threadIdx.x; k < NLAD + 1; k += blockDim.x)
        if (lh[k]) atomicAdd(&hist[k], lh[k]);
}

// ---------------------------------------------------------------------------
// Stage 5: replicate the while-loop: K = first level with count <= 2621.44
// ---------------------------------------------------------------------------
__global__ void eps_kernel(const unsigned int* __restrict__ hist, float* __restrict__ epsout) {
    if (threadIdx.x == 0) {
        float lad[NLAD];
        float e = 1e-5f;
        for (int k = 0; k < NLAD; ++k) { lad[k] = e; e *= 1.2f; }
        unsigned int suf[NLAD + 2];
        suf[NLAD + 1] = 0u;
        for (int k = NLAD; k >= 0; --k) suf[k] = suf[k + 1] + hist[k];
        // count(kl > lad[K]) = suf[K+1]
        int K = 0;
        while (K < NLAD - 1 && (float)suf[K + 1] > 2621.44f) K++;
        epsout[0] = lad[K];
    }
}

// ---------------------------------------------------------------------------
// Stage 6: direction loss. Inline 3x3 dilation of (kl > eps); argmin of 9
// shifted dists (first-occurrence tie-break, center last); per-pixel skip of
// the 8-neighbor KL softmax when invalid (~98% of lanes).
// ---------------------------------------------------------------------------
__global__ __launch_bounds__(256) void dir_kernel(const float* __restrict__ logits,
                                                  const float* __restrict__ klb,
                                                  const float* __restrict__ dist,
                                                  const float* __restrict__ epsp,
                                                  float* __restrict__ partials) {
    const int tid = threadIdx.x;
    const int b = blockIdx.z;
    const int i = blockIdx.y * TS + (tid >> 4);
    const int j = blockIdx.x * TS + (tid & 15);
    const float eps = epsp[0];
    const float* klp = klb + (size_t)b * NH * NW;
    const float* dp = dist + (size_t)b * NH * NW;

    // 3x3 dilation of bin mask (conv SAME with ones => any in clipped window)
    bool pb = false;
    for (int di = -1; di <= 1; ++di) {
        int ii = i + di; if (ii < 0 || ii >= NH) continue;
        for (int dj = -1; dj <= 1; ++dj) {
            int jj = j + dj; if (jj < 0 || jj >= NW) continue;
            if (klp[(size_t)ii * NW + jj] > eps) pb = true;
        }
    }

    const int dxs[9] = {1, -1, 0, 0, -1, 1, -1, 1, 0};
    const int dys[9] = {0, 0, -1, 1, 1, 1, -1, -1, 0};
    float dcen = dp[(size_t)i * NW + j];
    float best = MAXDIS; int gidx = 0;
#pragma unroll
    for (int k = 0; k < 9; ++k) {
        int ii = i + dxs[k], jj = j + dys[k];
        float v = (ii >= 0 && ii < NH && jj >= 0 && jj < NW) ? dp[(size_t)ii * NW + jj] : MAXDIS;
        if (k == 0) { best = v; gidx = 0; }
        else if (v < best) { best = v; gidx = k; }
    }
    bool valid = pb && (gidx != 8);

    float num = 0.f, vf = 0.f;
    if (valid) {
        vf = 1.f;
        const float* lcp = logits + (((size_t)b * NH + i) * NW + j) * NC;
        float lc[NC];
#pragma unroll
        for (int c = 0; c < NC; ++c) lc[c] = lcp[c];
        float mx = lc[0];
#pragma unroll
        for (int c = 1; c < NC; ++c) mx = fmaxf(mx, lc[c]);
        float se = 0.f;
#pragma unroll
        for (int c = 0; c < NC; ++c) se += expf(lc[c] - mx);
        float mc = mx + logf(se);
        float sumlc = 0.f;
#pragma unroll
        for (int c = 0; c < NC; ++c) sumlc += lc[c];

        float klm[8];
#pragma unroll
        for (int d = 0; d < 8; ++d) {
            int ii = i + dxs[d], jj = j + dys[d];
            if (ii >= 0 && ii < NH && jj >= 0 && jj < NW) {
                const float* lnp = logits + (((size_t)b * NH + ii) * NW + jj) * NC;
                float tv[NC], ev[NC];
#pragma unroll
                for (int c = 0; c < NC; ++c) tv[c] = lnp[c];
                float mxn = tv[0];
#pragma unroll
                for (int c = 1; c < NC; ++c) mxn = fmaxf(mxn, tv[c]);
                float sen = 0.f;
#pragma unroll
                for (int c = 0; c < NC; ++c) {
                    float s = tv[c] - mxn;
                    float eexp = expf(s);
                    ev[c] = eexp; sen += eexp; tv[c] = s;
                }
                float ls = logf(sen);
                float inv = 1.f / sen;
                float negH = 0.f, dot = 0.f;
#pragma unroll
                for (int c = 0; c < NC; ++c) {
                    float p = ev[c] * inv;
                    negH += p * (tv[c] - ls);
                    dot += p * lc[c];
                }
                klm[d] = negH + mc - dot;
            } else {
                // zero-padded neighbor logits: uniform distribution
                klm[d] = -logf(19.f) + mc - sumlc / 19.f;
            }
        }
        float m2 = klm[0];
#pragma unroll
        for (int d = 1; d < 8; ++d) m2 = fmaxf(m2, klm[d]);
        float s2 = 0.f;
#pragma unroll
        for (int d = 0; d < 8; ++d) s2 += expf(klm[d] - m2);
        float lse = m2 + logf(s2);
        float slp = 0.f;
        float klg = 0.f;
#pragma unroll
        for (int d = 0; d < 8; ++d) {
            slp += klm[d] - lse;
            if (d == gidx) klg = klm[d];        // static-index select, no scratch
        }
        float ce = -(0.2f / 8.f) * slp - 0.8f * (klg - lse);
        float w = fminf(dcen, 20.f) / 20.f;
        num = ce * w;
    }

    __shared__ float r1[256], r2[256];
    r1[tid] = num; r2[tid] = vf;
    __syncthreads();
    for (int s = 128; s > 0; s >>= 1) {
        if (tid < s) { r1[tid] += r1[tid + s]; r2[tid] += r2[tid + s]; }
        __syncthreads();
    }
    if (tid == 0) {
        int bid = (blockIdx.z * gridDim.y + blockIdx.y) * gridDim.x + blockIdx.x;
        partials[2 * bid] = r1[0];
        partials[2 * bid + 1] = r2[0];
    }
}

// ---------------------------------------------------------------------------
// Stage 7: deterministic final reduction
// ---------------------------------------------------------------------------
__global__ __launch_bounds__(256) void final_kernel(const float* __restrict__ partials,
                                                    float* __restrict__ out) {
    __shared__ float r1[256], r2[256];
    float s1 = 0.f, s2 = 0.f;
    for (int idx = threadIdx.x; idx < NPART; idx += 256) {
        s1 += partials[2 * idx];
        s2 += partials[2 * idx + 1];
    }
    r1[threadIdx.x] = s1; r2[threadIdx.x] = s2;
    __syncthreads();
    for (int s = 128; s > 0; s >>= 1) {
        if (threadIdx.x < s) { r1[threadIdx.x] += r1[threadIdx.x + s]; r2[threadIdx.x] += r2[threadIdx.x + s]; }
        __syncthreads();
    }
    if (threadIdx.x == 0) out[0] = r1[0] / fmaxf(r2[0], 1.f);
}

extern "C" void kernel_launch(void* const* d_in, const int* in_sizes, int n_in,
                              void* d_out, int out_size, void* d_ws, size_t ws_size,
                              hipStream_t stream) {
    const float* logits = (const float*)d_in[0];
    const int* target = (const int*)d_in[1];
    float* out = (float*)d_out;

    float* fws = (float*)d_ws;
    float* distb = fws;                       // NPIX floats (G2 then dist, in place)
    float* klb = fws + NPIX;                  // NPIX floats
    unsigned int* hist = (unsigned int*)(fws + 2 * (size_t)NPIX);  // 129 u32
    unsigned int* flags = hist + (NLAD + 1);                        // NB u32
    float* epsb = fws + 2 * (size_t)NPIX + 192;                     // 1 float
    float* partials = fws + 2 * (size_t)NPIX + 256;                 // 2*NPART floats

    // zero histogram + any_b flags (atomically accumulated each call)
    hipMemsetAsync(hist, 0, (NLAD + 1 + NB) * sizeof(unsigned int), stream);

    scan_kernel<<<(NB * NW + 255) / 256, 256, 0, stream>>>(target, distb, flags);
    rowmin_kernel<<<NB * NH, 256, 0, stream>>>(distb, flags);

    dim3 tiles(NW / TS, NH / TS, NB);
    kl_kernel<<<tiles, 256, 0, stream>>>(logits, klb);
    hist_kernel<<<1024, 256, 0, stream>>>(klb, hist);
    eps_kernel<<<1, 64, 0, stream>>>(hist, epsb);
    dir_kernel<<<tiles, 256, 0, stream>>>(logits, klb, distb, epsb, partials);
    final_kernel<<<1, 256, 0, stream>>>(partials, out);
}

// Round 2
// 547.945 us; speedup vs baseline: 1.1147x; 1.1147x over previous
//
#include <hip/hip_runtime.h>
#include <math.h>

#define NB 4
#define NH 512
#define NW 512
#define NC 19
#define NPIX (NB*NH*NW)
#define TS 16
#define NLAD 128
#define INF6 1.0e6f
#define MAXDIS 1.0e5f
#define NPART ((NW/TS)*(NH/TS)*NB)
#define NWRD 16          // 512 rows / 32 bits

// ---------------------------------------------------------------------------
// Stage 1a: boundary bitmasks. One thread per (b, word, column): builds a
// 32-row boundary mask word. Reads are row-major coalesced across lanes.
// bound = (gt==255) | (gt[i+1]!=gt[i]) | (gt[i][j+1]!=gt[i][j])  (zero-padded)
// ---------------------------------------------------------------------------
__global__ __launch_bounds__(256) void bound_kernel(const int* __restrict__ tgt,
                                                    unsigned int* __restrict__ maskw,
                                                    unsigned int* __restrict__ flags) {
    int cidx = blockIdx.x * 256 + threadIdx.x;          // [b][w][j]
    int j = cidx & (NW - 1);
    int w = (cidx >> 9) & (NWRD - 1);
    int b = cidx >> 13;
    if (b >= NB) return;
    const int* t = tgt + (size_t)b * NH * NW;
    unsigned int mask = 0u;
    int i0 = w * 32;
    int cur = t[(size_t)i0 * NW + j];
    for (int k = 0; k < 32; ++k) {
        int i = i0 + k;
        int nxt = (i + 1 < NH) ? t[(size_t)(i + 1) * NW + j] : cur;
        bool bnd = (cur == 255);
        if (i + 1 < NH && nxt != cur) bnd = true;
        if (j + 1 < NW && t[(size_t)i * NW + j + 1] != cur) bnd = true;
        if (bnd) mask |= (1u << k);
        cur = nxt;
    }
    maskw[cidx] = mask;
    if (mask) atomicOr(&flags[b], 1u);
}

// ---------------------------------------------------------------------------
// Stage 1b: vertical distance via nearest-set-bit. One thread per pixel.
// G = min(i - prevBound(i), nextBound(i) - i), saturating at 1e6 -> G^2.
// Exact f32 match of the reference scan (integer distances are exact).
// ---------------------------------------------------------------------------
__global__ __launch_bounds__(256) void vdist_kernel(const unsigned int* __restrict__ maskw,
                                                    float* __restrict__ g2) {
    int pix = blockIdx.x * 256 + threadIdx.x;
    if (pix >= NPIX) return;
    int b = pix >> 18;
    int rem = pix & (NH * NW - 1);
    int i = rem >> 9;
    int j = rem & (NW - 1);
    const unsigned int* mcol = maskw + (size_t)b * NWRD * NW;
    int wi = i >> 5, bi = i & 31;

    // down: nearest set bit at row <= i
    int down = 1 << 20;
    unsigned int m = mcol[(size_t)wi * NW + j] & ((2u << bi) - 1u);   // bits 0..bi
    if (m) down = bi - (31 - __clz(m));
    else {
        for (int w = wi - 1; w >= 0; --w) {
            unsigned int mm = mcol[(size_t)w * NW + j];
            if (mm) { down = bi + 32 * (wi - w) - (31 - __clz(mm)); break; }
        }
    }
    // up: nearest set bit at row >= i
    int up = 1 << 20;
    unsigned int mu = mcol[(size_t)wi * NW + j] & ~((1u << bi) - 1u); // bits bi..31
    if (mu) up = (__ffs(mu) - 1) - bi;
    else {
        for (int w = wi + 1; w < NWRD; ++w) {
            unsigned int mm = mcol[(size_t)w * NW + j];
            if (mm) { up = 32 * (w - wi) + (__ffs(mm) - 1) - bi; break; }
        }
    }
    int gi = min(down, up);
    float G = (gi >= (1 << 20)) ? INF6 : (float)gi;
    g2[pix] = G * G;
}

// ---------------------------------------------------------------------------
// Stage 2: row-wise D2 = min_j' (G2[j'] + (j-j')^2), expanding-window search
// then dist = max(sqrt(D2)-1, 0) * any_b. Overwrites g2 in place.
// ---------------------------------------------------------------------------
__global__ __launch_bounds__(256) void rowmin_kernel(float* __restrict__ g2,
                                                     const unsigned int* __restrict__ flags) {
    int row = blockIdx.x;              // b*NH + i
    int b = row / NH;
    float* g = g2 + (size_t)row * NW;
    __shared__ float s[NW];
    for (int j = threadIdx.x; j < NW; j += blockDim.x) s[j] = g[j];
    __syncthreads();
    bool has = flags[b] != 0u;
    for (int j = threadIdx.x; j < NW; j += blockDim.x) {
        float best = s[j];                       // jp == j term (off = 0)
        for (int r = 1; r < NW; ++r) {
            float rr = (float)(r * r);
            if (rr >= best) break;               // no farther jp can improve
            int jl = j - r, jr = j + r;
            if (jl >= 0) best = fminf(best, s[jl] + rr);
            if (jr < NW) best = fminf(best, s[jr] + rr);
        }
        g[j] = has ? fmaxf(sqrtf(best) - 1.f, 0.f) : 0.f;
    }
}

// ---------------------------------------------------------------------------
// Stage 3: kl = KL(P_ij||P_{i+1,j}) + KL(P_ij||P_{i,j+1})  (padded terms = 0)
// LDS-tiled 16x16 with bottom/right halo.
// ---------------------------------------------------------------------------
__global__ __launch_bounds__(256) void kl_kernel(const float* __restrict__ logits,
                                                 float* __restrict__ klb) {
    __shared__ float L[(TS + 1) * (TS + 1) * NC];   // 17*17*19 floats
    __shared__ float M[(TS + 1) * (TS + 1)];
    const int tid = threadIdx.x;
    const int b = blockIdx.z, i0 = blockIdx.y * TS, j0 = blockIdx.x * TS;
    const float* base = logits + ((size_t)b * NH * NW) * NC;
    const int lim = min((TS + 1) * NC, (NW - j0) * NC);
    for (int rr = 0; rr < TS + 1; ++rr) {
        const int gi = i0 + rr;
        if (gi < NH) {
            const float* src = base + ((size_t)gi * NW + j0) * NC;
            for (int t = tid; t < (TS + 1) * NC; t += 256)
                L[rr * (TS + 1) * NC + t] = (t < lim) ? src[t] : 0.f;
        } else {
            for (int t = tid; t < (TS + 1) * NC; t += 256)
                L[rr * (TS + 1) * NC + t] = 0.f;
        }
    }
    __syncthreads();
    for (int p = tid; p < (TS + 1) * (TS + 1); p += 256) {
        const float* v = &L[p * NC];
        float mx = v[0];
#pragma unroll
        for (int c = 1; c < NC; ++c) mx = fmaxf(mx, v[c]);
        float se = 0.f;
#pragma unroll
        for (int c = 0; c < NC; ++c) se += expf(v[c] - mx);
        M[p] = mx + logf(se);                    // logsumexp
    }
    __syncthreads();
    const int tx = tid & (TS - 1), ty = tid >> 4;
    const int gi = i0 + ty, gj = j0 + tx;
    const int p = ty * (TS + 1) + tx;
    const float* lc = &L[p * NC];
    const float mc = M[p];
    float pc[NC];
    float negH = 0.f;
#pragma unroll
    for (int c = 0; c < NC; ++c) {
        float s = lc[c] - mc;
        float e = expf(s);
        pc[c] = e;
        negH += e * s;
    }
    float kl = 0.f;
    if (gi < NH - 1) {
        const float* ln = &L[(p + TS + 1) * NC];
        float dot = 0.f;
#pragma unroll
        for (int c = 0; c < NC; ++c) dot += pc[c] * ln[c];
        kl += negH + M[p + TS + 1] - dot;
    }
    if (gj < NW - 1) {
        const float* ln = &L[(p + 1) * NC];
        float dot = 0.f;
#pragma unroll
        for (int c = 0; c < NC; ++c) dot += pc[c] * ln[c];
        kl += negH + M[p + 1] - dot;
    }
    klb[((size_t)b * NH + gi) * NW + gj] = kl;
}

// ---------------------------------------------------------------------------
// Stage 4: histogram of kl against the exact eps ladder (e = 1e-5; e *= 1.2f)
// ---------------------------------------------------------------------------
__global__ __launch_bounds__(256) void hist_kernel(const float* __restrict__ klb,
                                                   unsigned int* __restrict__ hist) {
    __shared__ float lad[NLAD];
    __shared__ unsigned int lh[NLAD + 1];
    if (threadIdx.x == 0) {
        float e = 1e-5f;
        for (int k = 0; k < NLAD; ++k) { lad[k] = e; e *= 1.2f; }
    }
    for (int k = threadIdx.x; k < NLAD + 1; k += blockDim.x) lh[k] = 0u;
    __syncthreads();
    for (size_t idx = (size_t)blockIdx.x * blockDim.x + threadIdx.x; idx < NPIX;
         idx += (size_t)gridDim.x * blockDim.x) {
        float v = klb[idx];
        int lo = 0, hi = NLAD;
        while (lo < hi) { int mid = (lo + hi) >> 1; if (v > lad[mid]) lo = mid + 1; else hi = mid; }
        atomicAdd(&lh[lo], 1u);
    }
    __syncthreads();
    for (int k = threadIdx.x; k < NLAD + 1; k += blockDim.x)
        if (lh[k]) atomicAdd(&hist[k], lh[k]);
}

// ---------------------------------------------------------------------------
// Stage 5: replicate the while-loop: K = first level with count <= 2621.44
// ---------------------------------------------------------------------------
__global__ void eps_kernel(const unsigned int* __restrict__ hist, float* __restrict__ epsout) {
    if (threadIdx.x == 0) {
        float lad[NLAD];
        float e = 1e-5f;
        for (int k = 0; k < NLAD; ++k) { lad[k] = e; e *= 1.2f; }
        unsigned int suf[NLAD + 2];
        suf[NLAD + 1] = 0u;
        for (int k = NLAD; k >= 0; --k) suf[k] = suf[k + 1] + hist[k];
        int K = 0;
        while (K < NLAD - 1 && (float)suf[K + 1] > 2621.44f) K++;
        epsout[0] = lad[K];
    }
}

// ---------------------------------------------------------------------------
// Stage 6: direction loss. Inline 3x3 dilation of (kl > eps); argmin of 9
// shifted dists; per-pixel skip of 8-neighbor KL softmax when invalid.
// ---------------------------------------------------------------------------
__global__ __launch_bounds__(256) void dir_kernel(const float* __restrict__ logits,
                                                  const float* __restrict__ klb,
                                                  const float* __restrict__ dist,
                                                  const float* __restrict__ epsp,
                                                  float* __restrict__ partials) {
    const int tid = threadIdx.x;
    const int b = blockIdx.z;
    const int i = blockIdx.y * TS + (tid >> 4);
    const int j = blockIdx.x * TS + (tid & 15);
    const float eps = epsp[0];
    const float* klp = klb + (size_t)b * NH * NW;
    const float* dp = dist + (size_t)b * NH * NW;

    bool pb = false;
    for (int di = -1; di <= 1; ++di) {
        int ii = i + di; if (ii < 0 || ii >= NH) continue;
        for (int dj = -1; dj <= 1; ++dj) {
            int jj = j + dj; if (jj < 0 || jj >= NW) continue;
            if (klp[(size_t)ii * NW + jj] > eps) pb = true;
        }
    }

    const int dxs[9] = {1, -1, 0, 0, -1, 1, -1, 1, 0};
    const int dys[9] = {0, 0, -1, 1, 1, 1, -1, -1, 0};
    float dcen = dp[(size_t)i * NW + j];
    float best = MAXDIS; int gidx = 0;
#pragma unroll
    for (int k = 0; k < 9; ++k) {
        int ii = i + dxs[k], jj = j + dys[k];
        float v = (ii >= 0 && ii < NH && jj >= 0 && jj < NW) ? dp[(size_t)ii * NW + jj] : MAXDIS;
        if (k == 0) { best = v; gidx = 0; }
        else if (v < best) { best = v; gidx = k; }
    }
    bool valid = pb && (gidx != 8);

    float num = 0.f, vf = 0.f;
    if (valid) {
        vf = 1.f;
        const float* lcp = logits + (((size_t)b * NH + i) * NW + j) * NC;
        float lc[NC];
#pragma unroll
        for (int c = 0; c < NC; ++c) lc[c] = lcp[c];
        float mx = lc[0];
#pragma unroll
        for (int c = 1; c < NC; ++c) mx = fmaxf(mx, lc[c]);
        float se = 0.f;
#pragma unroll
        for (int c = 0; c < NC; ++c) se += expf(lc[c] - mx);
        float mc = mx + logf(se);
        float sumlc = 0.f;
#pragma unroll
        for (int c = 0; c < NC; ++c) sumlc += lc[c];

        float klm[8];
#pragma unroll
        for (int d = 0; d < 8; ++d) {
            int ii = i + dxs[d], jj = j + dys[d];
            if (ii >= 0 && ii < NH && jj >= 0 && jj < NW) {
                const float* lnp = logits + (((size_t)b * NH + ii) * NW + jj) * NC;
                float tv[NC], ev[NC];
#pragma unroll
                for (int c = 0; c < NC; ++c) tv[c] = lnp[c];
                float mxn = tv[0];
#pragma unroll
                for (int c = 1; c < NC; ++c) mxn = fmaxf(mxn, tv[c]);
                float sen = 0.f;
#pragma unroll
                for (int c = 0; c < NC; ++c) {
                    float s = tv[c] - mxn;
                    float eexp = expf(s);
                    ev[c] = eexp; sen += eexp; tv[c] = s;
                }
                float ls = logf(sen);
                float inv = 1.f / sen;
                float negH = 0.f, dot = 0.f;
#pragma unroll
                for (int c = 0; c < NC; ++c) {
                    float p = ev[c] * inv;
                    negH += p * (tv[c] - ls);
                    dot += p * lc[c];
                }
                klm[d] = negH + mc - dot;
            } else {
                klm[d] = -logf(19.f) + mc - sumlc / 19.f;
            }
        }
        float m2 = klm[0];
#pragma unroll
        for (int d = 1; d < 8; ++d) m2 = fmaxf(m2, klm[d]);
        float s2 = 0.f;
#pragma unroll
        for (int d = 0; d < 8; ++d) s2 += expf(klm[d] - m2);
        float lse = m2 + logf(s2);
        float slp = 0.f;
        float klg = 0.f;
#pragma unroll
        for (int d = 0; d < 8; ++d) {
            slp += klm[d] - lse;
            if (d == gidx) klg = klm[d];
        }
        float ce = -(0.2f / 8.f) * slp - 0.8f * (klg - lse);
        float w = fminf(dcen, 20.f) / 20.f;
        num = ce * w;
    }

    __shared__ float r1[256], r2[256];
    r1[tid] = num; r2[tid] = vf;
    __syncthreads();
    for (int s = 128; s > 0; s >>= 1) {
        if (tid < s) { r1[tid] += r1[tid + s]; r2[tid] += r2[tid + s]; }
        __syncthreads();
    }
    if (tid == 0) {
        int bid = (blockIdx.z * gridDim.y + blockIdx.y) * gridDim.x + blockIdx.x;
        partials[2 * bid] = r1[0];
        partials[2 * bid + 1] = r2[0];
    }
}

// ---------------------------------------------------------------------------
// Stage 7: deterministic final reduction
// ---------------------------------------------------------------------------
__global__ __launch_bounds__(256) void final_kernel(const float* __restrict__ partials,
                                                    float* __restrict__ out) {
    __shared__ float r1[256], r2[256];
    float s1 = 0.f, s2 = 0.f;
    for (int idx = threadIdx.x; idx < NPART; idx += 256) {
        s1 += partials[2 * idx];
        s2 += partials[2 * idx + 1];
    }
    r1[threadIdx.x] = s1; r2[threadIdx.x] = s2;
    __syncthreads();
    for (int s = 128; s > 0; s >>= 1) {
        if (threadIdx.x < s) { r1[threadIdx.x] += r1[threadIdx.x + s]; r2[threadIdx.x] += r2[threadIdx.x + s]; }
        __syncthreads();
    }
    if (threadIdx.x == 0) out[0] = r1[0] / fmaxf(r2[0], 1.f);
}

extern "C" void kernel_launch(void* const* d_in, const int* in_sizes, int n_in,
                              void* d_out, int out_size, void* d_ws, size_t ws_size,
                              hipStream_t stream) {
    const float* logits = (const float*)d_in[0];
    const int* target = (const int*)d_in[1];
    float* out = (float*)d_out;

    float* fws = (float*)d_ws;
    float* distb = fws;                       // NPIX floats (G2 then dist, in place)
    float* klb = fws + NPIX;                  // NPIX floats
    unsigned int* hist = (unsigned int*)(fws + 2 * (size_t)NPIX);  // 129 u32
    unsigned int* flags = hist + (NLAD + 1);                        // NB u32
    float* epsb = fws + 2 * (size_t)NPIX + 192;                     // 1 float
    float* partials = fws + 2 * (size_t)NPIX + 256;                 // 2*NPART floats
    unsigned int* maskw = (unsigned int*)(fws + 2 * (size_t)NPIX + 256 + 2 * NPART);
                                              // NB*NWRD*NW u32 = 128 KB

    hipMemsetAsync(hist, 0, (NLAD + 1 + NB) * sizeof(unsigned int), stream);

    bound_kernel<<<(NB * NWRD * NW + 255) / 256, 256, 0, stream>>>(target, maskw, flags);
    vdist_kernel<<<(NPIX + 255) / 256, 256, 0, stream>>>(maskw, distb);
    rowmin_kernel<<<NB * NH, 256, 0, stream>>>(distb, flags);

    dim3 tiles(NW / TS, NH / TS, NB);
    kl_kernel<<<tiles, 256, 0, stream>>>(logits, klb);
    hist_kernel<<<1024, 256, 0, stream>>>(klb, hist);
    eps_kernel<<<1, 64, 0, stream>>>(hist, epsb);
    dir_kernel<<<tiles, 256, 0, stream>>>(logits, klb, distb, epsb, partials);
    final_kernel<<<1, 256, 0, stream>>>(partials, out);
}

// Round 3
// 187.046 us; speedup vs baseline: 3.2655x; 2.9295x over previous
//
#include <hip/hip_runtime.h>
#include <math.h>

#define NB 4
#define NH 512
#define NW 512
#define NC 19
#define NPIX (NB*NH*NW)
#define TS 16
#define NLAD 128
#define INF6 1.0e6f
#define MAXDIS 1.0e5f
#define NPART ((NW/TS)*(NH/TS)*NB)
#define NWRD 16          // 512 rows / 32 bits

// ---------------------------------------------------------------------------
// Stage 1a: boundary bitmasks. One thread per (b, word, column): builds a
// 32-row boundary mask word. Reads are row-major coalesced across lanes.
// bound = (gt==255) | (gt[i+1]!=gt[i]) | (gt[i][j+1]!=gt[i][j])  (zero-padded)
// atomicOr is wave-reduced: <=1 atomic per wave (b is wave-uniform).
// ---------------------------------------------------------------------------
__global__ __launch_bounds__(64) void bound_kernel(const int* __restrict__ tgt,
                                                   unsigned int* __restrict__ maskw,
                                                   unsigned int* __restrict__ flags) {
    int cidx = blockIdx.x * 64 + threadIdx.x;           // [b][w][j]
    int j = cidx & (NW - 1);
    int w = (cidx >> 9) & (NWRD - 1);
    int b = cidx >> 13;
    if (b >= NB) return;
    const int* t = tgt + (size_t)b * NH * NW;
    unsigned int mask = 0u;
    int i0 = w * 32;
    int cur = t[(size_t)i0 * NW + j];
    for (int k = 0; k < 32; ++k) {
        int i = i0 + k;
        int nxt = (i + 1 < NH) ? t[(size_t)(i + 1) * NW + j] : cur;
        bool bnd = (cur == 255);
        if (i + 1 < NH && nxt != cur) bnd = true;
        if (j + 1 < NW && t[(size_t)i * NW + j + 1] != cur) bnd = true;
        if (bnd) mask |= (1u << k);
        cur = nxt;
    }
    maskw[cidx] = mask;
    // wave-level reduction: one atomic per wave instead of per thread
    if (__any(mask != 0u) && (threadIdx.x & 63) == 0)
        atomicOr(&flags[b], 1u);
}

// ---------------------------------------------------------------------------
// Stage 1b: vertical distance via nearest-set-bit. One thread per pixel.
// G = min(i - prevBound(i), nextBound(i) - i), saturating at 1e6 -> G^2.
// Exact f32 match of the reference scan (integer distances are exact).
// ---------------------------------------------------------------------------
__global__ __launch_bounds__(256) void vdist_kernel(const unsigned int* __restrict__ maskw,
                                                    float* __restrict__ g2) {
    int pix = blockIdx.x * 256 + threadIdx.x;
    if (pix >= NPIX) return;
    int b = pix >> 18;
    int rem = pix & (NH * NW - 1);
    int i = rem >> 9;
    int j = rem & (NW - 1);
    const unsigned int* mcol = maskw + (size_t)b * NWRD * NW;
    int wi = i >> 5, bi = i & 31;

    // down: nearest set bit at row <= i
    int down = 1 << 20;
    unsigned int m = mcol[(size_t)wi * NW + j] & ((2u << bi) - 1u);   // bits 0..bi
    if (m) down = bi - (31 - __clz(m));
    else {
        for (int w = wi - 1; w >= 0; --w) {
            unsigned int mm = mcol[(size_t)w * NW + j];
            if (mm) { down = bi + 32 * (wi - w) - (31 - __clz(mm)); break; }
        }
    }
    // up: nearest set bit at row >= i
    int up = 1 << 20;
    unsigned int mu = mcol[(size_t)wi * NW + j] & ~((1u << bi) - 1u); // bits bi..31
    if (mu) up = (__ffs(mu) - 1) - bi;
    else {
        for (int w = wi + 1; w < NWRD; ++w) {
            unsigned int mm = mcol[(size_t)w * NW + j];
            if (mm) { up = 32 * (w - wi) + (__ffs(mm) - 1) - bi; break; }
        }
    }
    int gi = min(down, up);
    float G = (gi >= (1 << 20)) ? INF6 : (float)gi;
    g2[pix] = G * G;
}

// ---------------------------------------------------------------------------
// Stage 2: row-wise D2 = min_j' (G2[j'] + (j-j')^2), expanding-window search
// then dist = max(sqrt(D2)-1, 0) * any_b. Overwrites g2 in place.
// ---------------------------------------------------------------------------
__global__ __launch_bounds__(256) void rowmin_kernel(float* __restrict__ g2,
                                                     const unsigned int* __restrict__ flags) {
    int row = blockIdx.x;              // b*NH + i
    int b = row / NH;
    float* g = g2 + (size_t)row * NW;
    __shared__ float s[NW];
    for (int j = threadIdx.x; j < NW; j += blockDim.x) s[j] = g[j];
    __syncthreads();
    bool has = flags[b] != 0u;
    for (int j = threadIdx.x; j < NW; j += blockDim.x) {
        float best = s[j];                       // jp == j term (off = 0)
        for (int r = 1; r < NW; ++r) {
            float rr = (float)(r * r);
            if (rr >= best) break;               // no farther jp can improve
            int jl = j - r, jr = j + r;
            if (jl >= 0) best = fminf(best, s[jl] + rr);
            if (jr < NW) best = fminf(best, s[jr] + rr);
        }
        g[j] = has ? fmaxf(sqrtf(best) - 1.f, 0.f) : 0.f;
    }
}

// ---------------------------------------------------------------------------
// Stage 3: kl = KL(P_ij||P_{i+1,j}) + KL(P_ij||P_{i,j+1})  (padded terms = 0)
// LDS-tiled 16x16 with bottom/right halo.
// ---------------------------------------------------------------------------
__global__ __launch_bounds__(256) void kl_kernel(const float* __restrict__ logits,
                                                 float* __restrict__ klb) {
    __shared__ float L[(TS + 1) * (TS + 1) * NC];   // 17*17*19 floats
    __shared__ float M[(TS + 1) * (TS + 1)];
    const int tid = threadIdx.x;
    const int b = blockIdx.z, i0 = blockIdx.y * TS, j0 = blockIdx.x * TS;
    const float* base = logits + ((size_t)b * NH * NW) * NC;
    const int lim = min((TS + 1) * NC, (NW - j0) * NC);
    for (int rr = 0; rr < TS + 1; ++rr) {
        const int gi = i0 + rr;
        if (gi < NH) {
            const float* src = base + ((size_t)gi * NW + j0) * NC;
            for (int t = tid; t < (TS + 1) * NC; t += 256)
                L[rr * (TS + 1) * NC + t] = (t < lim) ? src[t] : 0.f;
        } else {
            for (int t = tid; t < (TS + 1) * NC; t += 256)
                L[rr * (TS + 1) * NC + t] = 0.f;
        }
    }
    __syncthreads();
    for (int p = tid; p < (TS + 1) * (TS + 1); p += 256) {
        const float* v = &L[p * NC];
        float mx = v[0];
#pragma unroll
        for (int c = 1; c < NC; ++c) mx = fmaxf(mx, v[c]);
        float se = 0.f;
#pragma unroll
        for (int c = 0; c < NC; ++c) se += expf(v[c] - mx);
        M[p] = mx + logf(se);                    // logsumexp
    }
    __syncthreads();
    const int tx = tid & (TS - 1), ty = tid >> 4;
    const int gi = i0 + ty, gj = j0 + tx;
    const int p = ty * (TS + 1) + tx;
    const float* lc = &L[p * NC];
    const float mc = M[p];
    float pc[NC];
    float negH = 0.f;
#pragma unroll
    for (int c = 0; c < NC; ++c) {
        float s = lc[c] - mc;
        float e = expf(s);
        pc[c] = e;
        negH += e * s;
    }
    float kl = 0.f;
    if (gi < NH - 1) {
        const float* ln = &L[(p + TS + 1) * NC];
        float dot = 0.f;
#pragma unroll
        for (int c = 0; c < NC; ++c) dot += pc[c] * ln[c];
        kl += negH + M[p + TS + 1] - dot;
    }
    if (gj < NW - 1) {
        const float* ln = &L[(p + 1) * NC];
        float dot = 0.f;
#pragma unroll
        for (int c = 0; c < NC; ++c) dot += pc[c] * ln[c];
        kl += negH + M[p + 1] - dot;
    }
    klb[((size_t)b * NH + gi) * NW + gj] = kl;
}

// ---------------------------------------------------------------------------
// Stage 4: histogram of kl against the exact eps ladder (e = 1e-5; e *= 1.2f)
// ---------------------------------------------------------------------------
__global__ __launch_bounds__(256) void hist_kernel(const float* __restrict__ klb,
                                                   unsigned int* __restrict__ hist) {
    __shared__ float lad[NLAD];
    __shared__ unsigned int lh[NLAD + 1];
    if (threadIdx.x == 0) {
        float e = 1e-5f;
        for (int k = 0; k < NLAD; ++k) { lad[k] = e; e *= 1.2f; }
    }
    for (int k = threadIdx.x; k < NLAD + 1; k += blockDim.x) lh[k] = 0u;
    __syncthreads();
    for (size_t idx = (size_t)blockIdx.x * blockDim.x + threadIdx.x; idx < NPIX;
         idx += (size_t)gridDim.x * blockDim.x) {
        float v = klb[idx];
        int lo = 0, hi = NLAD;
        while (lo < hi) { int mid = (lo + hi) >> 1; if (v > lad[mid]) lo = mid + 1; else hi = mid; }
        atomicAdd(&lh[lo], 1u);
    }
    __syncthreads();
    for (int k = threadIdx.x; k < NLAD + 1; k += blockDim.x)
        if (lh[k]) atomicAdd(&hist[k], lh[k]);
}

// ---------------------------------------------------------------------------
// Stage 5: replicate the while-loop: K = first level with count <= 2621.44
// ---------------------------------------------------------------------------
__global__ void eps_kernel(const unsigned int* __restrict__ hist, float* __restrict__ epsout) {
    if (threadIdx.x == 0) {
        float lad[NLAD];
        float e = 1e-5f;
        for (int k = 0; k < NLAD; ++k) { lad[k] = e; e *= 1.2f; }
        unsigned int suf[NLAD + 2];
        suf[NLAD + 1] = 0u;
        for (int k = NLAD; k >= 0; --k) suf[k] = suf[k + 1] + hist[k];
        int K = 0;
        while (K < NLAD - 1 && (float)suf[K + 1] > 2621.44f) K++;
        epsout[0] = lad[K];
    }
}

// ---------------------------------------------------------------------------
// Stage 6: direction loss. Inline 3x3 dilation of (kl > eps); argmin of 9
// shifted dists; per-pixel skip of 8-neighbor KL softmax when invalid.
// ---------------------------------------------------------------------------
__global__ __launch_bounds__(256) void dir_kernel(const float* __restrict__ logits,
                                                  const float* __restrict__ klb,
                                                  const float* __restrict__ dist,
                                                  const float* __restrict__ epsp,
                                                  float* __restrict__ partials) {
    const int tid = threadIdx.x;
    const int b = blockIdx.z;
    const int i = blockIdx.y * TS + (tid >> 4);
    const int j = blockIdx.x * TS + (tid & 15);
    const float eps = epsp[0];
    const float* klp = klb + (size_t)b * NH * NW;
    const float* dp = dist + (size_t)b * NH * NW;

    bool pb = false;
    for (int di = -1; di <= 1; ++di) {
        int ii = i + di; if (ii < 0 || ii >= NH) continue;
        for (int dj = -1; dj <= 1; ++dj) {
            int jj = j + dj; if (jj < 0 || jj >= NW) continue;
            if (klp[(size_t)ii * NW + jj] > eps) pb = true;
        }
    }

    const int dxs[9] = {1, -1, 0, 0, -1, 1, -1, 1, 0};
    const int dys[9] = {0, 0, -1, 1, 1, 1, -1, -1, 0};
    float dcen = dp[(size_t)i * NW + j];
    float best = MAXDIS; int gidx = 0;
#pragma unroll
    for (int k = 0; k < 9; ++k) {
        int ii = i + dxs[k], jj = j + dys[k];
        float v = (ii >= 0 && ii < NH && jj >= 0 && jj < NW) ? dp[(size_t)ii * NW + jj] : MAXDIS;
        if (k == 0) { best = v; gidx = 0; }
        else if (v < best) { best = v; gidx = k; }
    }
    bool valid = pb && (gidx != 8);

    float num = 0.f, vf = 0.f;
    if (valid) {
        vf = 1.f;
        const float* lcp = logits + (((size_t)b * NH + i) * NW + j) * NC;
        float lc[NC];
#pragma unroll
        for (int c = 0; c < NC; ++c) lc[c] = lcp[c];
        float mx = lc[0];
#pragma unroll
        for (int c = 1; c < NC; ++c) mx = fmaxf(mx, lc[c]);
        float se = 0.f;
#pragma unroll
        for (int c = 0; c < NC; ++c) se += expf(lc[c] - mx);
        float mc = mx + logf(se);
        float sumlc = 0.f;
#pragma unroll
        for (int c = 0; c < NC; ++c) sumlc += lc[c];

        float klm[8];
#pragma unroll
        for (int d = 0; d < 8; ++d) {
            int ii = i + dxs[d], jj = j + dys[d];
            if (ii >= 0 && ii < NH && jj >= 0 && jj < NW) {
                const float* lnp = logits + (((size_t)b * NH + ii) * NW + jj) * NC;
                float tv[NC], ev[NC];
#pragma unroll
                for (int c = 0; c < NC; ++c) tv[c] = lnp[c];
                float mxn = tv[0];
#pragma unroll
                for (int c = 1; c < NC; ++c) mxn = fmaxf(mxn, tv[c]);
                float sen = 0.f;
#pragma unroll
                for (int c = 0; c < NC; ++c) {
                    float s = tv[c] - mxn;
                    float eexp = expf(s);
                    ev[c] = eexp; sen += eexp; tv[c] = s;
                }
                float ls = logf(sen);
                float inv = 1.f / sen;
                float negH = 0.f, dot = 0.f;
#pragma unroll
                for (int c = 0; c < NC; ++c) {
                    float p = ev[c] * inv;
                    negH += p * (tv[c] - ls);
                    dot += p * lc[c];
                }
                klm[d] = negH + mc - dot;
            } else {
                klm[d] = -logf(19.f) + mc - sumlc / 19.f;
            }
        }
        float m2 = klm[0];
#pragma unroll
        for (int d = 1; d < 8; ++d) m2 = fmaxf(m2, klm[d]);
        float s2 = 0.f;
#pragma unroll
        for (int d = 0; d < 8; ++d) s2 += expf(klm[d] - m2);
        float lse = m2 + logf(s2);
        float slp = 0.f;
        float klg = 0.f;
#pragma unroll
        for (int d = 0; d < 8; ++d) {
            slp += klm[d] - lse;
            if (d == gidx) klg = klm[d];
        }
        float ce = -(0.2f / 8.f) * slp - 0.8f * (klg - lse);
        float w = fminf(dcen, 20.f) / 20.f;
        num = ce * w;
    }

    __shared__ float r1[256], r2[256];
    r1[tid] = num; r2[tid] = vf;
    __syncthreads();
    for (int s = 128; s > 0; s >>= 1) {
        if (tid < s) { r1[tid] += r1[tid + s]; r2[tid] += r2[tid + s]; }
        __syncthreads();
    }
    if (tid == 0) {
        int bid = (blockIdx.z * gridDim.y + blockIdx.y) * gridDim.x + blockIdx.x;
        partials[2 * bid] = r1[0];
        partials[2 * bid + 1] = r2[0];
    }
}

// ---------------------------------------------------------------------------
// Stage 7: deterministic final reduction
// ---------------------------------------------------------------------------
__global__ __launch_bounds__(256) void final_kernel(const float* __restrict__ partials,
                                                    float* __restrict__ out) {
    __shared__ float r1[256], r2[256];
    float s1 = 0.f, s2 = 0.f;
    for (int idx = threadIdx.x; idx < NPART; idx += 256) {
        s1 += partials[2 * idx];
        s2 += partials[2 * idx + 1];
    }
    r1[threadIdx.x] = s1; r2[threadIdx.x] = s2;
    __syncthreads();
    for (int s = 128; s > 0; s >>= 1) {
        if (threadIdx.x < s) { r1[threadIdx.x] += r1[threadIdx.x + s]; r2[threadIdx.x] += r2[threadIdx.x + s]; }
        __syncthreads();
    }
    if (threadIdx.x == 0) out[0] = r1[0] / fmaxf(r2[0], 1.f);
}

extern "C" void kernel_launch(void* const* d_in, const int* in_sizes, int n_in,
                              void* d_out, int out_size, void* d_ws, size_t ws_size,
                              hipStream_t stream) {
    const float* logits = (const float*)d_in[0];
    const int* target = (const int*)d_in[1];
    float* out = (float*)d_out;

    float* fws = (float*)d_ws;
    float* distb = fws;                       // NPIX floats (G2 then dist, in place)
    float* klb = fws + NPIX;                  // NPIX floats
    unsigned int* hist = (unsigned int*)(fws + 2 * (size_t)NPIX);  // 129 u32
    unsigned int* flags = hist + (NLAD + 1);                        // NB u32
    float* epsb = fws + 2 * (size_t)NPIX + 192;                     // 1 float
    float* partials = fws + 2 * (size_t)NPIX + 256;                 // 2*NPART floats
    unsigned int* maskw = (unsigned int*)(fws + 2 * (size_t)NPIX + 256 + 2 * NPART);
                                              // NB*NWRD*NW u32 = 128 KB

    hipMemsetAsync(hist, 0, (NLAD + 1 + NB) * sizeof(unsigned int), stream);

    bound_kernel<<<NB * NWRD * NW / 64, 64, 0, stream>>>(target, maskw, flags);
    vdist_kernel<<<(NPIX + 255) / 256, 256, 0, stream>>>(maskw, distb);
    rowmin_kernel<<<NB * NH, 256, 0, stream>>>(distb, flags);

    dim3 tiles(NW / TS, NH / TS, NB);
    kl_kernel<<<tiles, 256, 0, stream>>>(logits, klb);
    hist_kernel<<<1024, 256, 0, stream>>>(klb, hist);
    eps_kernel<<<1, 64, 0, stream>>>(hist, epsb);
    dir_kernel<<<tiles, 256, 0, stream>>>(logits, klb, distb, epsb, partials);
    final_kernel<<<1, 256, 0, stream>>>(partials, out);
}

// Round 4
// 168.623 us; speedup vs baseline: 3.6222x; 1.1093x over previous
//
#include <hip/hip_runtime.h>
#include <math.h>

#define NB 4
#define NH 512
#define NW 512
#define NC 19
#define NPIX (NB*NH*NW)
#define TS 16
#define NLAD 128
#define INF6 1.0e6f
#define MAXDIS 1.0e5f
#define NPART ((NW/TS)*(NH/TS)*NB)
#define NWRD 16          // 512 rows / 32 bits
#define NREP 8           // histogram replicas (atomic contention spread)
#define HSTRIDE 132      // padded per-replica stride (129 bins)

// ---------------------------------------------------------------------------
// Stage 1a: boundary bitmasks. One thread per (b, word, column).
// ---------------------------------------------------------------------------
__global__ __launch_bounds__(64) void bound_kernel(const int* __restrict__ tgt,
                                                   unsigned int* __restrict__ maskw,
                                                   unsigned int* __restrict__ flags) {
    int cidx = blockIdx.x * 64 + threadIdx.x;           // [b][w][j]
    int j = cidx & (NW - 1);
    int w = (cidx >> 9) & (NWRD - 1);
    int b = cidx >> 13;
    if (b >= NB) return;
    const int* t = tgt + (size_t)b * NH * NW;
    unsigned int mask = 0u;
    int i0 = w * 32;
    int cur = t[(size_t)i0 * NW + j];
    for (int k = 0; k < 32; ++k) {
        int i = i0 + k;
        int nxt = (i + 1 < NH) ? t[(size_t)(i + 1) * NW + j] : cur;
        bool bnd = (cur == 255);
        if (i + 1 < NH && nxt != cur) bnd = true;
        if (j + 1 < NW && t[(size_t)i * NW + j + 1] != cur) bnd = true;
        if (bnd) mask |= (1u << k);
        cur = nxt;
    }
    maskw[cidx] = mask;
    if (__any(mask != 0u) && (threadIdx.x & 63) == 0)
        atomicOr(&flags[b], 1u);
}

// ---------------------------------------------------------------------------
// Stage 1b: vertical distance via nearest-set-bit. One thread per pixel.
// ---------------------------------------------------------------------------
__global__ __launch_bounds__(256) void vdist_kernel(const unsigned int* __restrict__ maskw,
                                                    float* __restrict__ g2) {
    int pix = blockIdx.x * 256 + threadIdx.x;
    if (pix >= NPIX) return;
    int b = pix >> 18;
    int rem = pix & (NH * NW - 1);
    int i = rem >> 9;
    int j = rem & (NW - 1);
    const unsigned int* mcol = maskw + (size_t)b * NWRD * NW;
    int wi = i >> 5, bi = i & 31;

    int down = 1 << 20;
    unsigned int m = mcol[(size_t)wi * NW + j] & ((2u << bi) - 1u);
    if (m) down = bi - (31 - __clz(m));
    else {
        for (int w = wi - 1; w >= 0; --w) {
            unsigned int mm = mcol[(size_t)w * NW + j];
            if (mm) { down = bi + 32 * (wi - w) - (31 - __clz(mm)); break; }
        }
    }
    int up = 1 << 20;
    unsigned int mu = mcol[(size_t)wi * NW + j] & ~((1u << bi) - 1u);
    if (mu) up = (__ffs(mu) - 1) - bi;
    else {
        for (int w = wi + 1; w < NWRD; ++w) {
            unsigned int mm = mcol[(size_t)w * NW + j];
            if (mm) { up = 32 * (w - wi) + (__ffs(mm) - 1) - bi; break; }
        }
    }
    int gi = min(down, up);
    float G = (gi >= (1 << 20)) ? INF6 : (float)gi;
    g2[pix] = G * G;
}

// ---------------------------------------------------------------------------
// Stage 2: row-wise min-plus transform -> final distance map (in place).
// ---------------------------------------------------------------------------
__global__ __launch_bounds__(256) void rowmin_kernel(float* __restrict__ g2,
                                                     const unsigned int* __restrict__ flags) {
    int row = blockIdx.x;              // b*NH + i
    int b = row / NH;
    float* g = g2 + (size_t)row * NW;
    __shared__ float s[NW];
    for (int j = threadIdx.x; j < NW; j += blockDim.x) s[j] = g[j];
    __syncthreads();
    bool has = flags[b] != 0u;
    for (int j = threadIdx.x; j < NW; j += blockDim.x) {
        float best = s[j];
        for (int r = 1; r < NW; ++r) {
            float rr = (float)(r * r);
            if (rr >= best) break;
            int jl = j - r, jr = j + r;
            if (jl >= 0) best = fminf(best, s[jl] + rr);
            if (jr < NW) best = fminf(best, s[jr] + rr);
        }
        g[j] = has ? fmaxf(sqrtf(best) - 1.f, 0.f) : 0.f;
    }
}

// ---------------------------------------------------------------------------
// Stage 3a: per-pixel log-sum-exp map. Block = 256 consecutive pixels of one
// row-chunk; float4-staged to LDS (coalesced, 16B-aligned), reg reduce.
// ---------------------------------------------------------------------------
__global__ __launch_bounds__(256) void lse_kernel(const float* __restrict__ logits,
                                                  float* __restrict__ lsem) {
    __shared__ float4 S4[1216];                 // 256*19 floats
    const int tid = threadIdx.x;
    const size_t pix0 = (size_t)blockIdx.x * 256;
    const float4* src = reinterpret_cast<const float4*>(logits + pix0 * NC);
#pragma unroll
    for (int t = 0; t < 5; ++t) {
        int idx = tid + t * 256;
        if (idx < 1216) S4[idx] = src[idx];
    }
    __syncthreads();
    const float* L = (const float*)S4;
    const float* v = &L[tid * NC];
    float mx = v[0];
#pragma unroll
    for (int c = 1; c < NC; ++c) mx = fmaxf(mx, v[c]);
    float se = 0.f;
#pragma unroll
    for (int c = 0; c < NC; ++c) se += expf(v[c] - mx);
    lsem[pix0 + tid] = mx + logf(se);
}

// ---------------------------------------------------------------------------
// Stage 3b: kl = [negH + lse_dn - dot(p, l_dn)] + [negH + lse_rt - dot(p, l_rt)]
// Block = 256-pixel row chunk; stages center chunk (+right halo) and the
// row-below chunk as float4. Fused per-block histogram (8-replica merge).
// ---------------------------------------------------------------------------
__global__ __launch_bounds__(256) void klhist_kernel(const float* __restrict__ logits,
                                                     const float* __restrict__ lsem,
                                                     float* __restrict__ klb,
                                                     unsigned int* __restrict__ hist) {
    __shared__ float4 Lc4[1221];                // up to (256+1)*19 floats (+pad)
    __shared__ float4 Ld4[1216];                // 256*19 floats
    __shared__ float lad[NLAD];
    __shared__ unsigned int lh[NLAD + 1];
    const int tid = threadIdx.x;
    const int cid = blockIdx.x;
    const int j0 = (cid & 1) * 256;
    const int i = (cid >> 1) & (NH - 1);
    const int b = cid >> 10;

    if (tid == 0) {
        float e = 1e-5f;
        for (int k = 0; k < NLAD; ++k) { lad[k] = e; e *= 1.2f; }
    }
    if (tid < NLAD + 1) lh[tid] = 0u;

    const size_t rowpix = (size_t)(b * NH + i) * NW + j0;
    const float4* src = reinterpret_cast<const float4*>(logits + rowpix * NC);
    const int n4c = (j0 == 0) ? 1221 : 1216;    // halo pixel only when it exists
#pragma unroll
    for (int t = 0; t < 5; ++t) {
        int idx = tid + t * 256;
        if (idx < n4c) Lc4[idx] = src[idx];
    }
    if (i < NH - 1) {
        const float4* srcd = reinterpret_cast<const float4*>(logits + (rowpix + NW) * NC);
#pragma unroll
        for (int t = 0; t < 5; ++t) {
            int idx = tid + t * 256;
            if (idx < 1216) Ld4[idx] = srcd[idx];
        }
    }
    __syncthreads();

    const float* Lc = (const float*)Lc4;
    const float* Ld = (const float*)Ld4;
    const int j = j0 + tid;
    const size_t pix = rowpix + tid;
    const float lse_c = lsem[pix];
    const float lse_r = (j < NW - 1) ? lsem[pix + 1] : 0.f;
    const float lse_d = (i < NH - 1) ? lsem[pix + NW] : 0.f;

    const float* lc = &Lc[tid * NC];
    const float* lr = &Lc[(tid + 1) * NC];      // garbage when j==NW-1 (masked)
    const float* ld = &Ld[tid * NC];            // garbage when i==NH-1 (masked)
    float negH = 0.f, dotr = 0.f, dotd = 0.f;
#pragma unroll
    for (int c = 0; c < NC; ++c) {
        float s = lc[c] - lse_c;
        float p = expf(s);
        negH += p * s;
        dotr += p * lr[c];
        dotd += p * ld[c];
    }
    float kl = 0.f;
    if (i < NH - 1) kl += negH + lse_d - dotd;
    if (j < NW - 1) kl += negH + lse_r - dotr;
    klb[pix] = kl;

    // fused histogram: bin = first ladder level k with kl <= lad[k]
    int lo = 0, hi = NLAD;
    while (lo < hi) { int mid = (lo + hi) >> 1; if (kl > lad[mid]) lo = mid + 1; else hi = mid; }
    atomicAdd(&lh[lo], 1u);
    __syncthreads();
    if (tid < NLAD + 1 && lh[tid])
        atomicAdd(&hist[(cid & (NREP - 1)) * HSTRIDE + tid], lh[tid]);
}

// ---------------------------------------------------------------------------
// Stage 5: replicate the while-loop: K = first level with count <= 2621.44
// ---------------------------------------------------------------------------
__global__ void eps_kernel(const unsigned int* __restrict__ hist, float* __restrict__ epsout) {
    __shared__ unsigned int tot[NLAD + 1];
    int k = threadIdx.x;
    if (k < NLAD + 1) {
        unsigned int s = 0;
        for (int r = 0; r < NREP; ++r) s += hist[r * HSTRIDE + k];
        tot[k] = s;
    }
    __syncthreads();
    if (k == 0) {
        float lad[NLAD];
        float e = 1e-5f;
        for (int q = 0; q < NLAD; ++q) { lad[q] = e; e *= 1.2f; }
        unsigned int suf[NLAD + 2];
        suf[NLAD + 1] = 0u;
        for (int q = NLAD; q >= 0; --q) suf[q] = suf[q + 1] + tot[q];
        int K = 0;
        while (K < NLAD - 1 && (float)suf[K + 1] > 2621.44f) K++;
        epsout[0] = lad[K];
    }
}

// ---------------------------------------------------------------------------
// Stage 6: direction loss. Inline 3x3 dilation of (kl > eps); argmin of 9
// shifted dists; per-pixel skip of 8-neighbor KL softmax when invalid.
// ---------------------------------------------------------------------------
__global__ __launch_bounds__(256) void dir_kernel(const float* __restrict__ logits,
                                                  const float* __restrict__ klb,
                                                  const float* __restrict__ dist,
                                                  const float* __restrict__ epsp,
                                                  float* __restrict__ partials) {
    const int tid = threadIdx.x;
    const int b = blockIdx.z;
    const int i = blockIdx.y * TS + (tid >> 4);
    const int j = blockIdx.x * TS + (tid & 15);
    const float eps = epsp[0];
    const float* klp = klb + (size_t)b * NH * NW;
    const float* dp = dist + (size_t)b * NH * NW;

    bool pb = false;
    for (int di = -1; di <= 1; ++di) {
        int ii = i + di; if (ii < 0 || ii >= NH) continue;
        for (int dj = -1; dj <= 1; ++dj) {
            int jj = j + dj; if (jj < 0 || jj >= NW) continue;
            if (klp[(size_t)ii * NW + jj] > eps) pb = true;
        }
    }

    const int dxs[9] = {1, -1, 0, 0, -1, 1, -1, 1, 0};
    const int dys[9] = {0, 0, -1, 1, 1, 1, -1, -1, 0};
    float dcen = dp[(size_t)i * NW + j];
    float best = MAXDIS; int gidx = 0;
#pragma unroll
    for (int k = 0; k < 9; ++k) {
        int ii = i + dxs[k], jj = j + dys[k];
        float v = (ii >= 0 && ii < NH && jj >= 0 && jj < NW) ? dp[(size_t)ii * NW + jj] : MAXDIS;
        if (k == 0) { best = v; gidx = 0; }
        else if (v < best) { best = v; gidx = k; }
    }
    bool valid = pb && (gidx != 8);

    float num = 0.f, vf = 0.f;
    if (valid) {
        vf = 1.f;
        const float* lcp = logits + (((size_t)b * NH + i) * NW + j) * NC;
        float lc[NC];
#pragma unroll
        for (int c = 0; c < NC; ++c) lc[c] = lcp[c];
        float mx = lc[0];
#pragma unroll
        for (int c = 1; c < NC; ++c) mx = fmaxf(mx, lc[c]);
        float se = 0.f;
#pragma unroll
        for (int c = 0; c < NC; ++c) se += expf(lc[c] - mx);
        float mc = mx + logf(se);
        float sumlc = 0.f;
#pragma unroll
        for (int c = 0; c < NC; ++c) sumlc += lc[c];

        float klm[8];
#pragma unroll
        for (int d = 0; d < 8; ++d) {
            int ii = i + dxs[d], jj = j + dys[d];
            if (ii >= 0 && ii < NH && jj >= 0 && jj < NW) {
                const float* lnp = logits + (((size_t)b * NH + ii) * NW + jj) * NC;
                float tv[NC], ev[NC];
#pragma unroll
                for (int c = 0; c < NC; ++c) tv[c] = lnp[c];
                float mxn = tv[0];
#pragma unroll
                for (int c = 1; c < NC; ++c) mxn = fmaxf(mxn, tv[c]);
                float sen = 0.f;
#pragma unroll
                for (int c = 0; c < NC; ++c) {
                    float s = tv[c] - mxn;
                    float eexp = expf(s);
                    ev[c] = eexp; sen += eexp; tv[c] = s;
                }
                float ls = logf(sen);
                float inv = 1.f / sen;
                float negH = 0.f, dot = 0.f;
#pragma unroll
                for (int c = 0; c < NC; ++c) {
                    float p = ev[c] * inv;
                    negH += p * (tv[c] - ls);
                    dot += p * lc[c];
                }
                klm[d] = negH + mc - dot;
            } else {
                klm[d] = -logf(19.f) + mc - sumlc / 19.f;
            }
        }
        float m2 = klm[0];
#pragma unroll
        for (int d = 1; d < 8; ++d) m2 = fmaxf(m2, klm[d]);
        float s2 = 0.f;
#pragma unroll
        for (int d = 0; d < 8; ++d) s2 += expf(klm[d] - m2);
        float lse = m2 + logf(s2);
        float slp = 0.f;
        float klg = 0.f;
#pragma unroll
        for (int d = 0; d < 8; ++d) {
            slp += klm[d] - lse;
            if (d == gidx) klg = klm[d];
        }
        float ce = -(0.2f / 8.f) * slp - 0.8f * (klg - lse);
        float w = fminf(dcen, 20.f) / 20.f;
        num = ce * w;
    }

    __shared__ float r1[256], r2[256];
    r1[tid] = num; r2[tid] = vf;
    __syncthreads();
    for (int s = 128; s > 0; s >>= 1) {
        if (tid < s) { r1[tid] += r1[tid + s]; r2[tid] += r2[tid + s]; }
        __syncthreads();
    }
    if (tid == 0) {
        int bid = (blockIdx.z * gridDim.y + blockIdx.y) * gridDim.x + blockIdx.x;
        partials[2 * bid] = r1[0];
        partials[2 * bid + 1] = r2[0];
    }
}

// ---------------------------------------------------------------------------
// Stage 7: deterministic final reduction
// ---------------------------------------------------------------------------
__global__ __launch_bounds__(256) void final_kernel(const float* __restrict__ partials,
                                                    float* __restrict__ out) {
    __shared__ float r1[256], r2[256];
    float s1 = 0.f, s2 = 0.f;
    for (int idx = threadIdx.x; idx < NPART; idx += 256) {
        s1 += partials[2 * idx];
        s2 += partials[2 * idx + 1];
    }
    r1[threadIdx.x] = s1; r2[threadIdx.x] = s2;
    __syncthreads();
    for (int s = 128; s > 0; s >>= 1) {
        if (threadIdx.x < s) { r1[threadIdx.x] += r1[threadIdx.x + s]; r2[threadIdx.x] += r2[threadIdx.x + s]; }
        __syncthreads();
    }
    if (threadIdx.x == 0) out[0] = r1[0] / fmaxf(r2[0], 1.f);
}

extern "C" void kernel_launch(void* const* d_in, const int* in_sizes, int n_in,
                              void* d_out, int out_size, void* d_ws, size_t ws_size,
                              hipStream_t stream) {
    const float* logits = (const float*)d_in[0];
    const int* target = (const int*)d_in[1];
    float* out = (float*)d_out;

    float* fws = (float*)d_ws;
    float* distb = fws;                         // NPIX floats
    float* klb = fws + NPIX;                    // NPIX floats
    float* lsem = fws + 2 * (size_t)NPIX;       // NPIX floats
    unsigned int* hist = (unsigned int*)(fws + 3 * (size_t)NPIX);   // NREP*HSTRIDE u32
    unsigned int* flags = hist + NREP * HSTRIDE;                    // NB u32
    float* epsb = fws + 3 * (size_t)NPIX + 2048;                    // 1 float
    float* partials = epsb + 64;                                    // 2*NPART floats
    unsigned int* maskw = (unsigned int*)(partials + 2 * NPART);    // NB*NWRD*NW u32

    hipMemsetAsync(hist, 0, (NREP * HSTRIDE + NB) * sizeof(unsigned int), stream);

    bound_kernel<<<NB * NWRD * NW / 64, 64, 0, stream>>>(target, maskw, flags);
    vdist_kernel<<<(NPIX + 255) / 256, 256, 0, stream>>>(maskw, distb);
    rowmin_kernel<<<NB * NH, 256, 0, stream>>>(distb, flags);

    lse_kernel<<<NPIX / 256, 256, 0, stream>>>(logits, lsem);
    klhist_kernel<<<NB * NH * 2, 256, 0, stream>>>(logits, lsem, klb, hist);
    eps_kernel<<<1, 256, 0, stream>>>(hist, epsb);

    dim3 tiles(NW / TS, NH / TS, NB);
    dir_kernel<<<tiles, 256, 0, stream>>>(logits, klb, distb, epsb, partials);
    final_kernel<<<1, 256, 0, stream>>>(partials, out);
}

// Round 5
// 134.623 us; speedup vs baseline: 4.5371x; 1.2526x over previous
//
#include <hip/hip_runtime.h>
#include <math.h>

#define NB 4
#define NH 512
#define NW 512
#define NC 19
#define NPIX (NB*NH*NW)
#define TS 16
#define NLAD 128
#define INF6 1.0e6f
#define MAXDIS 1.0e5f
#define NWRD 16          // 512 rows / 32 bits
#define NREP 8           // histogram replicas
#define HSTRIDE 132      // padded per-replica stride (129 bins)
#define NSEG 128         // compaction segments (separate counter cache lines-ish)
#define SEGCAP 512       // entries per segment (expected max ~250)

// ---------------------------------------------------------------------------
// Stage 1a: boundary bitmasks. One thread per (b, word, column).
// ---------------------------------------------------------------------------
__global__ __launch_bounds__(64) void bound_kernel(const int* __restrict__ tgt,
                                                   unsigned int* __restrict__ maskw,
                                                   unsigned int* __restrict__ flags) {
    int cidx = blockIdx.x * 64 + threadIdx.x;           // [b][w][j]
    int j = cidx & (NW - 1);
    int w = (cidx >> 9) & (NWRD - 1);
    int b = cidx >> 13;
    if (b >= NB) return;
    const int* t = tgt + (size_t)b * NH * NW;
    unsigned int mask = 0u;
    int i0 = w * 32;
    int cur = t[(size_t)i0 * NW + j];
    for (int k = 0; k < 32; ++k) {
        int i = i0 + k;
        int nxt = (i + 1 < NH) ? t[(size_t)(i + 1) * NW + j] : cur;
        bool bnd = (cur == 255);
        if (i + 1 < NH && nxt != cur) bnd = true;
        if (j + 1 < NW && t[(size_t)i * NW + j + 1] != cur) bnd = true;
        if (bnd) mask |= (1u << k);
        cur = nxt;
    }
    maskw[cidx] = mask;
    if (__any(mask != 0u) && (threadIdx.x & 63) == 0)
        atomicOr(&flags[b], 1u);
}

// ---------------------------------------------------------------------------
// Stage 1b: vertical distance via nearest-set-bit. One thread per pixel.
// ---------------------------------------------------------------------------
__global__ __launch_bounds__(256) void vdist_kernel(const unsigned int* __restrict__ maskw,
                                                    float* __restrict__ g2) {
    int pix = blockIdx.x * 256 + threadIdx.x;
    if (pix >= NPIX) return;
    int b = pix >> 18;
    int rem = pix & (NH * NW - 1);
    int i = rem >> 9;
    int j = rem & (NW - 1);
    const unsigned int* mcol = maskw + (size_t)b * NWRD * NW;
    int wi = i >> 5, bi = i & 31;

    int down = 1 << 20;
    unsigned int m = mcol[(size_t)wi * NW + j] & ((2u << bi) - 1u);
    if (m) down = bi - (31 - __clz(m));
    else {
        for (int w = wi - 1; w >= 0; --w) {
            unsigned int mm = mcol[(size_t)w * NW + j];
            if (mm) { down = bi + 32 * (wi - w) - (31 - __clz(mm)); break; }
        }
    }
    int up = 1 << 20;
    unsigned int mu = mcol[(size_t)wi * NW + j] & ~((1u << bi) - 1u);
    if (mu) up = (__ffs(mu) - 1) - bi;
    else {
        for (int w = wi + 1; w < NWRD; ++w) {
            unsigned int mm = mcol[(size_t)w * NW + j];
            if (mm) { up = 32 * (w - wi) + (__ffs(mm) - 1) - bi; break; }
        }
    }
    int gi = min(down, up);
    float G = (gi >= (1 << 20)) ? INF6 : (float)gi;
    g2[pix] = G * G;
}

// ---------------------------------------------------------------------------
// Stage 2: row-wise min-plus transform -> final distance map (in place).
// ---------------------------------------------------------------------------
__global__ __launch_bounds__(256) void rowmin_kernel(float* __restrict__ g2,
                                                     const unsigned int* __restrict__ flags) {
    int row = blockIdx.x;              // b*NH + i
    int b = row / NH;
    float* g = g2 + (size_t)row * NW;
    __shared__ float s[NW];
    for (int j = threadIdx.x; j < NW; j += blockDim.x) s[j] = g[j];
    __syncthreads();
    bool has = flags[b] != 0u;
    for (int j = threadIdx.x; j < NW; j += blockDim.x) {
        float best = s[j];
        for (int r = 1; r < NW; ++r) {
            float rr = (float)(r * r);
            if (rr >= best) break;
            int jl = j - r, jr = j + r;
            if (jl >= 0) best = fminf(best, s[jl] + rr);
            if (jr < NW) best = fminf(best, s[jr] + rr);
        }
        g[j] = has ? fmaxf(sqrtf(best) - 1.f, 0.f) : 0.f;
    }
}

// ---------------------------------------------------------------------------
// Stage 3a: per-pixel log-sum-exp map (float4-staged to LDS, reg reduce).
// ---------------------------------------------------------------------------
__global__ __launch_bounds__(256) void lse_kernel(const float* __restrict__ logits,
                                                  float* __restrict__ lsem) {
    __shared__ float4 S4[1216];                 // 256*19 floats
    const int tid = threadIdx.x;
    const size_t pix0 = (size_t)blockIdx.x * 256;
    const float4* src = reinterpret_cast<const float4*>(logits + pix0 * NC);
#pragma unroll
    for (int t = 0; t < 5; ++t) {
        int idx = tid + t * 256;
        if (idx < 1216) S4[idx] = src[idx];
    }
    __syncthreads();
    const float* L = (const float*)S4;
    const float* v = &L[tid * NC];
    float mx = v[0];
#pragma unroll
    for (int c = 1; c < NC; ++c) mx = fmaxf(mx, v[c]);
    float se = 0.f;
#pragma unroll
    for (int c = 0; c < NC; ++c) se += expf(v[c] - mx);
    lsem[pix0 + tid] = mx + logf(se);
}

// ---------------------------------------------------------------------------
// Stage 3b: kl map + fused 8-replica histogram.
// ---------------------------------------------------------------------------
__global__ __launch_bounds__(256) void klhist_kernel(const float* __restrict__ logits,
                                                     const float* __restrict__ lsem,
                                                     float* __restrict__ klb,
                                                     unsigned int* __restrict__ hist) {
    __shared__ float4 Lc4[1221];
    __shared__ float4 Ld4[1216];
    __shared__ float lad[NLAD];
    __shared__ unsigned int lh[NLAD + 1];
    const int tid = threadIdx.x;
    const int cid = blockIdx.x;
    const int j0 = (cid & 1) * 256;
    const int i = (cid >> 1) & (NH - 1);
    const int b = cid >> 10;

    if (tid == 0) {
        float e = 1e-5f;
        for (int k = 0; k < NLAD; ++k) { lad[k] = e; e *= 1.2f; }
    }
    if (tid < NLAD + 1) lh[tid] = 0u;

    const size_t rowpix = (size_t)(b * NH + i) * NW + j0;
    const float4* src = reinterpret_cast<const float4*>(logits + rowpix * NC);
    const int n4c = (j0 == 0) ? 1221 : 1216;
#pragma unroll
    for (int t = 0; t < 5; ++t) {
        int idx = tid + t * 256;
        if (idx < n4c) Lc4[idx] = src[idx];
    }
    if (i < NH - 1) {
        const float4* srcd = reinterpret_cast<const float4*>(logits + (rowpix + NW) * NC);
#pragma unroll
        for (int t = 0; t < 5; ++t) {
            int idx = tid + t * 256;
            if (idx < 1216) Ld4[idx] = srcd[idx];
        }
    }
    __syncthreads();

    const float* Lc = (const float*)Lc4;
    const float* Ld = (const float*)Ld4;
    const int j = j0 + tid;
    const size_t pix = rowpix + tid;
    const float lse_c = lsem[pix];
    const float lse_r = (j < NW - 1) ? lsem[pix + 1] : 0.f;
    const float lse_d = (i < NH - 1) ? lsem[pix + NW] : 0.f;

    const float* lc = &Lc[tid * NC];
    const float* lr = &Lc[(tid + 1) * NC];
    const float* ld = &Ld[tid * NC];
    float negH = 0.f, dotr = 0.f, dotd = 0.f;
#pragma unroll
    for (int c = 0; c < NC; ++c) {
        float s = lc[c] - lse_c;
        float p = expf(s);
        negH += p * s;
        dotr += p * lr[c];
        dotd += p * ld[c];
    }
    float kl = 0.f;
    if (i < NH - 1) kl += negH + lse_d - dotd;
    if (j < NW - 1) kl += negH + lse_r - dotr;
    klb[pix] = kl;

    int lo = 0, hi = NLAD;
    while (lo < hi) { int mid = (lo + hi) >> 1; if (kl > lad[mid]) lo = mid + 1; else hi = mid; }
    atomicAdd(&lh[lo], 1u);
    __syncthreads();
    if (tid < NLAD + 1 && lh[tid])
        atomicAdd(&hist[(cid & (NREP - 1)) * HSTRIDE + tid], lh[tid]);
}

// ---------------------------------------------------------------------------
// Stage 5: eps selection (exact while-loop replication).
// ---------------------------------------------------------------------------
__global__ void eps_kernel(const unsigned int* __restrict__ hist, float* __restrict__ epsout) {
    __shared__ unsigned int tot[NLAD + 1];
    int k = threadIdx.x;
    if (k < NLAD + 1) {
        unsigned int s = 0;
        for (int r = 0; r < NREP; ++r) s += hist[r * HSTRIDE + k];
        tot[k] = s;
    }
    __syncthreads();
    if (k == 0) {
        float lad[NLAD];
        float e = 1e-5f;
        for (int q = 0; q < NLAD; ++q) { lad[q] = e; e *= 1.2f; }
        unsigned int suf[NLAD + 2];
        suf[NLAD + 1] = 0u;
        for (int q = NLAD; q >= 0; --q) suf[q] = suf[q + 1] + tot[q];
        int K = 0;
        while (K < NLAD - 1 && (float)suf[K + 1] > 2621.44f) K++;
        epsout[0] = lad[K];
    }
}

// ---------------------------------------------------------------------------
// Stage 6a: validity pass (dilation + argmin only) + wave-ballot compaction
// into 128 segments (contention spread across counter lines).
// ---------------------------------------------------------------------------
__global__ __launch_bounds__(256) void valid_kernel(const float* __restrict__ klb,
                                                    const float* __restrict__ dist,
                                                    const float* __restrict__ epsp,
                                                    unsigned int* __restrict__ cnts,
                                                    unsigned int* __restrict__ list) {
    const int tid = threadIdx.x;
    const int b = blockIdx.z;
    const int i = blockIdx.y * TS + (tid >> 4);
    const int j = blockIdx.x * TS + (tid & 15);
    const float eps = epsp[0];
    const float* klp = klb + (size_t)b * NH * NW;
    const float* dp = dist + (size_t)b * NH * NW;

    bool pb = false;
    for (int di = -1; di <= 1; ++di) {
        int ii = i + di; if (ii < 0 || ii >= NH) continue;
        for (int dj = -1; dj <= 1; ++dj) {
            int jj = j + dj; if (jj < 0 || jj >= NW) continue;
            if (klp[(size_t)ii * NW + jj] > eps) pb = true;
        }
    }

    const int dxs[9] = {1, -1, 0, 0, -1, 1, -1, 1, 0};
    const int dys[9] = {0, 0, -1, 1, 1, 1, -1, -1, 0};
    float best = MAXDIS; int gidx = 0;
#pragma unroll
    for (int k = 0; k < 9; ++k) {
        int ii = i + dxs[k], jj = j + dys[k];
        float v = (ii >= 0 && ii < NH && jj >= 0 && jj < NW) ? dp[(size_t)ii * NW + jj] : MAXDIS;
        if (k == 0) { best = v; gidx = 0; }
        else if (v < best) { best = v; gidx = k; }
    }
    bool valid = pb && (gidx != 8);

    const int pix = (b * NH + i) * NW + j;
    const int lane = tid & 63;
    unsigned long long mk = __ballot(valid);
    int cnt = __popcll(mk);
    int flatw = (((blockIdx.z * gridDim.y + blockIdx.y) * gridDim.x + blockIdx.x) << 2) | (tid >> 6);
    int seg = flatw & (NSEG - 1);
    unsigned int base = 0u;
    if (lane == 0 && cnt) base = atomicAdd(&cnts[seg], (unsigned int)cnt);
    base = (unsigned int)__shfl((int)base, 0, 64);
    if (valid) {
        unsigned int off = base + (unsigned int)__popcll(mk & ((1ull << lane) - 1ull));
        if (off < SEGCAP)
            list[seg * SEGCAP + off] = (unsigned int)pix | ((unsigned int)gidx << 20);
    }
}

// ---------------------------------------------------------------------------
// Stage 6b: CE over valid pixels only. 8 lanes per pixel (one per neighbor);
// neighbor LSE reused from lsem; width-8 shuffle reductions for the softmax.
// Writes ce*w into dense cearr[pix] (deterministic final sum).
// ---------------------------------------------------------------------------
__global__ __launch_bounds__(256) void dirce_kernel(const float* __restrict__ logits,
                                                    const float* __restrict__ lsem,
                                                    const float* __restrict__ dist,
                                                    const unsigned int* __restrict__ cnts,
                                                    const unsigned int* __restrict__ list,
                                                    float* __restrict__ cearr) {
    const int t = blockIdx.x * 256 + threadIdx.x;
    const int e = t >> 3;                       // entry
    const int d = t & 7;                        // neighbor lane
    const int s = e >> 9;                       // segment (SEGCAP=512)
    const int k = e & (SEGCAP - 1);
    unsigned int cs = cnts[s];
    if ((unsigned int)k >= min(cs, (unsigned int)SEGCAP)) return;
    unsigned int w = list[s * SEGCAP + k];
    const int pix = (int)(w & (NPIX - 1));
    const int gidx = (int)(w >> 20);
    const int j = pix & (NW - 1);
    const int i = (pix >> 9) & (NH - 1);

    // packed neighbor offset tables: dx+1, dy+1 in 2-bit fields
    const unsigned int DXP = (2u<<0)|(0u<<2)|(1u<<4)|(1u<<6)|(0u<<8)|(2u<<10)|(0u<<12)|(2u<<14);
    const unsigned int DYP = (1u<<0)|(1u<<2)|(0u<<4)|(2u<<6)|(2u<<8)|(2u<<10)|(0u<<12)|(0u<<14);
    const int dx = (int)((DXP >> (2 * d)) & 3u) - 1;
    const int dy = (int)((DYP >> (2 * d)) & 3u) - 1;
    const int ii = i + dx, jj = j + dy;
    const bool inb = (ii >= 0 && ii < NH && jj >= 0 && jj < NW);

    const float lse_c = lsem[pix];
    const float* lcp = logits + (size_t)pix * NC;
    float lc[NC];
    float sumlc = 0.f;
#pragma unroll
    for (int c = 0; c < NC; ++c) { lc[c] = lcp[c]; sumlc += lc[c]; }

    float klm;
    if (inb) {
        const int npix = pix + dx * NW + dy;
        const float lse_n = lsem[npix];
        const float* lnp = logits + (size_t)npix * NC;
        float negH = 0.f, dot = 0.f;
#pragma unroll
        for (int c = 0; c < NC; ++c) {
            float sv = lnp[c] - lse_n;
            float p = expf(sv);
            negH += p * sv;
            dot += p * lc[c];
        }
        klm = negH + lse_c - dot;
    } else {
        klm = -logf(19.f) + lse_c - sumlc / 19.f;
    }

    // width-8 group softmax-CE
    float m2 = klm;
#pragma unroll
    for (int o = 4; o > 0; o >>= 1) m2 = fmaxf(m2, __shfl_xor(m2, o, 8));
    float ex = expf(klm - m2);
    float s2 = ex;
#pragma unroll
    for (int o = 4; o > 0; o >>= 1) s2 += __shfl_xor(s2, o, 8);
    float lse = m2 + logf(s2);
    float lp = klm - lse;
    float slp = lp;
#pragma unroll
    for (int o = 4; o > 0; o >>= 1) slp += __shfl_xor(slp, o, 8);
    float kg = (d == gidx) ? lp : 0.f;
#pragma unroll
    for (int o = 4; o > 0; o >>= 1) kg += __shfl_xor(kg, o, 8);

    if (d == 0) {
        float ce = -(0.2f / 8.f) * slp - 0.8f * kg;
        float wgt = fminf(dist[pix], 20.f) / 20.f;
        cearr[pix] = ce * wgt;
    }
}

// ---------------------------------------------------------------------------
// Stage 7a: block-tree reduce of dense cearr (1024 floats/block, fixed order).
// ---------------------------------------------------------------------------
__global__ __launch_bounds__(256) void redA_kernel(const float4* __restrict__ cearr4,
                                                   float* __restrict__ partials) {
    __shared__ float r[256];
    const int tid = threadIdx.x;
    float4 v = cearr4[(size_t)blockIdx.x * 256 + tid];
    r[tid] = (v.x + v.y) + (v.z + v.w);
    __syncthreads();
    for (int s = 128; s > 0; s >>= 1) {
        if (tid < s) r[tid] += r[tid + s];
        __syncthreads();
    }
    if (tid == 0) partials[blockIdx.x] = r[0];
}

// ---------------------------------------------------------------------------
// Stage 7b: final: sum partials + valid count -> loss.
// ---------------------------------------------------------------------------
__global__ __launch_bounds__(256) void redB_kernel(const float* __restrict__ partials,
                                                   const unsigned int* __restrict__ cnts,
                                                   float* __restrict__ out) {
    __shared__ float r[256];
    const int tid = threadIdx.x;
    r[tid] = partials[tid] + partials[tid + 256] + partials[tid + 512] + partials[tid + 768];
    __syncthreads();
    for (int s = 128; s > 0; s >>= 1) {
        if (tid < s) r[tid] += r[tid + s];
        __syncthreads();
    }
    if (tid == 0) {
        unsigned int vf = 0;
        for (int q = 0; q < NSEG; ++q) vf += cnts[q];
        out[0] = r[0] / fmaxf((float)vf, 1.f);
    }
}

extern "C" void kernel_launch(void* const* d_in, const int* in_sizes, int n_in,
                              void* d_out, int out_size, void* d_ws, size_t ws_size,
                              hipStream_t stream) {
    const float* logits = (const float*)d_in[0];
    const int* target = (const int*)d_in[1];
    float* out = (float*)d_out;

    float* fws = (float*)d_ws;
    float* distb = fws;                         // NPIX floats
    float* klb = fws + NPIX;                    // NPIX floats (reused as cearr)
    float* lsem = fws + 2 * (size_t)NPIX;       // NPIX floats
    unsigned int* hist = (unsigned int*)(fws + 3 * (size_t)NPIX);   // NREP*HSTRIDE
    unsigned int* flags = hist + NREP * HSTRIDE;                    // NB
    unsigned int* cnts = flags + NB;                                // NSEG
    float* epsb = (float*)(cnts + NSEG);                            // 1 (+pad)
    unsigned int* list = (unsigned int*)(epsb + 64);                // NSEG*SEGCAP
    float* partials = (float*)(list + NSEG * SEGCAP);               // 1024
    unsigned int* maskw = (unsigned int*)(partials + 1024);         // NB*NWRD*NW

    // zero histogram + flags + segment counters (contiguous)
    hipMemsetAsync(hist, 0, (NREP * HSTRIDE + NB + NSEG) * sizeof(unsigned int), stream);

    bound_kernel<<<NB * NWRD * NW / 64, 64, 0, stream>>>(target, maskw, flags);
    vdist_kernel<<<(NPIX + 255) / 256, 256, 0, stream>>>(maskw, distb);
    rowmin_kernel<<<NB * NH, 256, 0, stream>>>(distb, flags);

    lse_kernel<<<NPIX / 256, 256, 0, stream>>>(logits, lsem);
    klhist_kernel<<<NB * NH * 2, 256, 0, stream>>>(logits, lsem, klb, hist);
    eps_kernel<<<1, 256, 0, stream>>>(hist, epsb);

    dim3 tiles(NW / TS, NH / TS, NB);
    valid_kernel<<<tiles, 256, 0, stream>>>(klb, distb, epsb, cnts, list);

    // klb's kl values are consumed; reuse the buffer as dense ce accumulator
    float* cearr = klb;
    hipMemsetAsync(cearr, 0, (size_t)NPIX * sizeof(float), stream);

    dirce_kernel<<<NSEG * SEGCAP * 8 / 256, 256, 0, stream>>>(logits, lsem, distb,
                                                              cnts, list, cearr);
    redA_kernel<<<1024, 256, 0, stream>>>((const float4*)cearr, partials);
    redB_kernel<<<1, 256, 0, stream>>>(partials, cnts, out);
}

// Round 6
// 129.171 us; speedup vs baseline: 4.7285x; 1.0422x over previous
//
#include <hip/hip_runtime.h>
#include <math.h>

#define NB 4
#define NH 512
#define NW 512
#define NC 19
#define NPIX (NB*NH*NW)
#define TS 16
#define NLAD 128
#define INF6 1.0e6f
#define MAXDIS 1.0e5f
#define NWRD 16          // 512 rows / 32 bits
#define NREP 8           // histogram replicas
#define HSTRIDE 132      // padded per-replica stride (129 bins)
#define NSEG 128         // compaction segments
#define SEGCAP 512       // entries per segment (expected max ~250)

// ---------------------------------------------------------------------------
// Stage 1a: boundary bitmasks. One thread per (b, word, column).
// ---------------------------------------------------------------------------
__global__ __launch_bounds__(64) void bound_kernel(const int* __restrict__ tgt,
                                                   unsigned int* __restrict__ maskw,
                                                   unsigned int* __restrict__ flags) {
    int cidx = blockIdx.x * 64 + threadIdx.x;           // [b][w][j]
    int j = cidx & (NW - 1);
    int w = (cidx >> 9) & (NWRD - 1);
    int b = cidx >> 13;
    if (b >= NB) return;
    const int* t = tgt + (size_t)b * NH * NW;
    unsigned int mask = 0u;
    int i0 = w * 32;
    int cur = t[(size_t)i0 * NW + j];
    for (int k = 0; k < 32; ++k) {
        int i = i0 + k;
        int nxt = (i + 1 < NH) ? t[(size_t)(i + 1) * NW + j] : cur;
        bool bnd = (cur == 255);
        if (i + 1 < NH && nxt != cur) bnd = true;
        if (j + 1 < NW && t[(size_t)i * NW + j + 1] != cur) bnd = true;
        if (bnd) mask |= (1u << k);
        cur = nxt;
    }
    maskw[cidx] = mask;
    if (__any(mask != 0u) && (threadIdx.x & 63) == 0)
        atomicOr(&flags[b], 1u);
}

// ---------------------------------------------------------------------------
// Stage 1b: vertical distance via nearest-set-bit. One thread per pixel.
// ---------------------------------------------------------------------------
__global__ __launch_bounds__(256) void vdist_kernel(const unsigned int* __restrict__ maskw,
                                                    float* __restrict__ g2) {
    int pix = blockIdx.x * 256 + threadIdx.x;
    if (pix >= NPIX) return;
    int b = pix >> 18;
    int rem = pix & (NH * NW - 1);
    int i = rem >> 9;
    int j = rem & (NW - 1);
    const unsigned int* mcol = maskw + (size_t)b * NWRD * NW;
    int wi = i >> 5, bi = i & 31;

    int down = 1 << 20;
    unsigned int m = mcol[(size_t)wi * NW + j] & ((2u << bi) - 1u);
    if (m) down = bi - (31 - __clz(m));
    else {
        for (int w = wi - 1; w >= 0; --w) {
            unsigned int mm = mcol[(size_t)w * NW + j];
            if (mm) { down = bi + 32 * (wi - w) - (31 - __clz(mm)); break; }
        }
    }
    int up = 1 << 20;
    unsigned int mu = mcol[(size_t)wi * NW + j] & ~((1u << bi) - 1u);
    if (mu) up = (__ffs(mu) - 1) - bi;
    else {
        for (int w = wi + 1; w < NWRD; ++w) {
            unsigned int mm = mcol[(size_t)w * NW + j];
            if (mm) { up = 32 * (w - wi) + (__ffs(mm) - 1) - bi; break; }
        }
    }
    int gi = min(down, up);
    float G = (gi >= (1 << 20)) ? INF6 : (float)gi;
    g2[pix] = G * G;
}

// ---------------------------------------------------------------------------
// Stage 2: row-wise min-plus transform -> final distance map (in place).
// ---------------------------------------------------------------------------
__global__ __launch_bounds__(256) void rowmin_kernel(float* __restrict__ g2,
                                                     const unsigned int* __restrict__ flags) {
    int row = blockIdx.x;              // b*NH + i
    int b = row / NH;
    float* g = g2 + (size_t)row * NW;
    __shared__ float s[NW];
    for (int j = threadIdx.x; j < NW; j += blockDim.x) s[j] = g[j];
    __syncthreads();
    bool has = flags[b] != 0u;
    for (int j = threadIdx.x; j < NW; j += blockDim.x) {
        float best = s[j];
        for (int r = 1; r < NW; ++r) {
            float rr = (float)(r * r);
            if (rr >= best) break;
            int jl = j - r, jr = j + r;
            if (jl >= 0) best = fminf(best, s[jl] + rr);
            if (jr < NW) best = fminf(best, s[jr] + rr);
        }
        g[j] = has ? fmaxf(sqrtf(best) - 1.f, 0.f) : 0.f;
    }
}

// ---------------------------------------------------------------------------
// Stage 3a: per-pixel log-sum-exp map (float4-staged to LDS, reg reduce).
// Also zero-fills the dense ce accumulator (fused: coalesced linear stream,
// replaces the 46us rocclr fillBuffer dispatch).
// ---------------------------------------------------------------------------
__global__ __launch_bounds__(256) void lse_kernel(const float* __restrict__ logits,
                                                  float* __restrict__ lsem,
                                                  float* __restrict__ cearr) {
    __shared__ float4 S4[1216];                 // 256*19 floats
    const int tid = threadIdx.x;
    const size_t pix0 = (size_t)blockIdx.x * 256;
    const float4* src = reinterpret_cast<const float4*>(logits + pix0 * NC);
#pragma unroll
    for (int t = 0; t < 5; ++t) {
        int idx = tid + t * 256;
        if (idx < 1216) S4[idx] = src[idx];
    }
    cearr[pix0 + tid] = 0.f;
    __syncthreads();
    const float* L = (const float*)S4;
    const float* v = &L[tid * NC];
    float mx = v[0];
#pragma unroll
    for (int c = 1; c < NC; ++c) mx = fmaxf(mx, v[c]);
    float se = 0.f;
#pragma unroll
    for (int c = 0; c < NC; ++c) se += expf(v[c] - mx);
    lsem[pix0 + tid] = mx + logf(se);
}

// ---------------------------------------------------------------------------
// Stage 3b: kl map + fused 8-replica histogram.
// ---------------------------------------------------------------------------
__global__ __launch_bounds__(256) void klhist_kernel(const float* __restrict__ logits,
                                                     const float* __restrict__ lsem,
                                                     float* __restrict__ klb,
                                                     unsigned int* __restrict__ hist) {
    __shared__ float4 Lc4[1221];
    __shared__ float4 Ld4[1216];
    __shared__ float lad[NLAD];
    __shared__ unsigned int lh[NLAD + 1];
    const int tid = threadIdx.x;
    const int cid = blockIdx.x;
    const int j0 = (cid & 1) * 256;
    const int i = (cid >> 1) & (NH - 1);
    const int b = cid >> 10;

    if (tid == 0) {
        float e = 1e-5f;
        for (int k = 0; k < NLAD; ++k) { lad[k] = e; e *= 1.2f; }
    }
    if (tid < NLAD + 1) lh[tid] = 0u;

    const size_t rowpix = (size_t)(b * NH + i) * NW + j0;
    const float4* src = reinterpret_cast<const float4*>(logits + rowpix * NC);
    const int n4c = (j0 == 0) ? 1221 : 1216;
#pragma unroll
    for (int t = 0; t < 5; ++t) {
        int idx = tid + t * 256;
        if (idx < n4c) Lc4[idx] = src[idx];
    }
    if (i < NH - 1) {
        const float4* srcd = reinterpret_cast<const float4*>(logits + (rowpix + NW) * NC);
#pragma unroll
        for (int t = 0; t < 5; ++t) {
            int idx = tid + t * 256;
            if (idx < 1216) Ld4[idx] = srcd[idx];
        }
    }
    __syncthreads();

    const float* Lc = (const float*)Lc4;
    const float* Ld = (const float*)Ld4;
    const int j = j0 + tid;
    const size_t pix = rowpix + tid;
    const float lse_c = lsem[pix];
    const float lse_r = (j < NW - 1) ? lsem[pix + 1] : 0.f;
    const float lse_d = (i < NH - 1) ? lsem[pix + NW] : 0.f;

    const float* lc = &Lc[tid * NC];
    const float* lr = &Lc[(tid + 1) * NC];
    const float* ld = &Ld[tid * NC];
    float negH = 0.f, dotr = 0.f, dotd = 0.f;
#pragma unroll
    for (int c = 0; c < NC; ++c) {
        float s = lc[c] - lse_c;
        float p = expf(s);
        negH += p * s;
        dotr += p * lr[c];
        dotd += p * ld[c];
    }
    float kl = 0.f;
    if (i < NH - 1) kl += negH + lse_d - dotd;
    if (j < NW - 1) kl += negH + lse_r - dotr;
    klb[pix] = kl;

    int lo = 0, hi = NLAD;
    while (lo < hi) { int mid = (lo + hi) >> 1; if (kl > lad[mid]) lo = mid + 1; else hi = mid; }
    atomicAdd(&lh[lo], 1u);
    __syncthreads();
    if (tid < NLAD + 1 && lh[tid])
        atomicAdd(&hist[(cid & (NREP - 1)) * HSTRIDE + tid], lh[tid]);
}

// ---------------------------------------------------------------------------
// Stage 5: eps selection (exact while-loop replication).
// ---------------------------------------------------------------------------
__global__ void eps_kernel(const unsigned int* __restrict__ hist, float* __restrict__ epsout) {
    __shared__ unsigned int tot[NLAD + 1];
    int k = threadIdx.x;
    if (k < NLAD + 1) {
        unsigned int s = 0;
        for (int r = 0; r < NREP; ++r) s += hist[r * HSTRIDE + k];
        tot[k] = s;
    }
    __syncthreads();
    if (k == 0) {
        float lad[NLAD];
        float e = 1e-5f;
        for (int q = 0; q < NLAD; ++q) { lad[q] = e; e *= 1.2f; }
        unsigned int suf[NLAD + 2];
        suf[NLAD + 1] = 0u;
        for (int q = NLAD; q >= 0; --q) suf[q] = suf[q + 1] + tot[q];
        int K = 0;
        while (K < NLAD - 1 && (float)suf[K + 1] > 2621.44f) K++;
        epsout[0] = lad[K];
    }
}

// ---------------------------------------------------------------------------
// Stage 6a: validity pass (dilation + argmin only) + wave-ballot compaction.
// ---------------------------------------------------------------------------
__global__ __launch_bounds__(256) void valid_kernel(const float* __restrict__ klb,
                                                    const float* __restrict__ dist,
                                                    const float* __restrict__ epsp,
                                                    unsigned int* __restrict__ cnts,
                                                    unsigned int* __restrict__ list) {
    const int tid = threadIdx.x;
    const int b = blockIdx.z;
    const int i = blockIdx.y * TS + (tid >> 4);
    const int j = blockIdx.x * TS + (tid & 15);
    const float eps = epsp[0];
    const float* klp = klb + (size_t)b * NH * NW;
    const float* dp = dist + (size_t)b * NH * NW;

    bool pb = false;
    for (int di = -1; di <= 1; ++di) {
        int ii = i + di; if (ii < 0 || ii >= NH) continue;
        for (int dj = -1; dj <= 1; ++dj) {
            int jj = j + dj; if (jj < 0 || jj >= NW) continue;
            if (klp[(size_t)ii * NW + jj] > eps) pb = true;
        }
    }

    const int dxs[9] = {1, -1, 0, 0, -1, 1, -1, 1, 0};
    const int dys[9] = {0, 0, -1, 1, 1, 1, -1, -1, 0};
    float best = MAXDIS; int gidx = 0;
#pragma unroll
    for (int k = 0; k < 9; ++k) {
        int ii = i + dxs[k], jj = j + dys[k];
        float v = (ii >= 0 && ii < NH && jj >= 0 && jj < NW) ? dp[(size_t)ii * NW + jj] : MAXDIS;
        if (k == 0) { best = v; gidx = 0; }
        else if (v < best) { best = v; gidx = k; }
    }
    bool valid = pb && (gidx != 8);

    const int pix = (b * NH + i) * NW + j;
    const int lane = tid & 63;
    unsigned long long mk = __ballot(valid);
    int cnt = __popcll(mk);
    int flatw = (((blockIdx.z * gridDim.y + blockIdx.y) * gridDim.x + blockIdx.x) << 2) | (tid >> 6);
    int seg = flatw & (NSEG - 1);
    unsigned int base = 0u;
    if (lane == 0 && cnt) base = atomicAdd(&cnts[seg], (unsigned int)cnt);
    base = (unsigned int)__shfl((int)base, 0, 64);
    if (valid) {
        unsigned int off = base + (unsigned int)__popcll(mk & ((1ull << lane) - 1ull));
        if (off < SEGCAP)
            list[seg * SEGCAP + off] = (unsigned int)pix | ((unsigned int)gidx << 20);
    }
}

// ---------------------------------------------------------------------------
// Stage 6b: CE over valid pixels only. 8 lanes per pixel (one per neighbor).
// ---------------------------------------------------------------------------
__global__ __launch_bounds__(256) void dirce_kernel(const float* __restrict__ logits,
                                                    const float* __restrict__ lsem,
                                                    const float* __restrict__ dist,
                                                    const unsigned int* __restrict__ cnts,
                                                    const unsigned int* __restrict__ list,
                                                    float* __restrict__ cearr) {
    const int t = blockIdx.x * 256 + threadIdx.x;
    const int e = t >> 3;                       // entry
    const int d = t & 7;                        // neighbor lane
    const int s = e >> 9;                       // segment (SEGCAP=512)
    const int k = e & (SEGCAP - 1);
    unsigned int cs = cnts[s];
    if ((unsigned int)k >= min(cs, (unsigned int)SEGCAP)) return;
    unsigned int w = list[s * SEGCAP + k];
    const int pix = (int)(w & (NPIX - 1));
    const int gidx = (int)(w >> 20);
    const int j = pix & (NW - 1);
    const int i = (pix >> 9) & (NH - 1);

    const unsigned int DXP = (2u<<0)|(0u<<2)|(1u<<4)|(1u<<6)|(0u<<8)|(2u<<10)|(0u<<12)|(2u<<14);
    const unsigned int DYP = (1u<<0)|(1u<<2)|(0u<<4)|(2u<<6)|(2u<<8)|(2u<<10)|(0u<<12)|(0u<<14);
    const int dx = (int)((DXP >> (2 * d)) & 3u) - 1;
    const int dy = (int)((DYP >> (2 * d)) & 3u) - 1;
    const int ii = i + dx, jj = j + dy;
    const bool inb = (ii >= 0 && ii < NH && jj >= 0 && jj < NW);

    const float lse_c = lsem[pix];
    const float* lcp = logits + (size_t)pix * NC;
    float lc[NC];
    float sumlc = 0.f;
#pragma unroll
    for (int c = 0; c < NC; ++c) { lc[c] = lcp[c]; sumlc += lc[c]; }

    float klm;
    if (inb) {
        const int npix = pix + dx * NW + dy;
        const float lse_n = lsem[npix];
        const float* lnp = logits + (size_t)npix * NC;
        float negH = 0.f, dot = 0.f;
#pragma unroll
        for (int c = 0; c < NC; ++c) {
            float sv = lnp[c] - lse_n;
            float p = expf(sv);
            negH += p * sv;
            dot += p * lc[c];
        }
        klm = negH + lse_c - dot;
    } else {
        klm = -logf(19.f) + lse_c - sumlc / 19.f;
    }

    float m2 = klm;
#pragma unroll
    for (int o = 4; o > 0; o >>= 1) m2 = fmaxf(m2, __shfl_xor(m2, o, 8));
    float ex = expf(klm - m2);
    float s2 = ex;
#pragma unroll
    for (int o = 4; o > 0; o >>= 1) s2 += __shfl_xor(s2, o, 8);
    float lse = m2 + logf(s2);
    float lp = klm - lse;
    float slp = lp;
#pragma unroll
    for (int o = 4; o > 0; o >>= 1) slp += __shfl_xor(slp, o, 8);
    float kg = (d == gidx) ? lp : 0.f;
#pragma unroll
    for (int o = 4; o > 0; o >>= 1) kg += __shfl_xor(kg, o, 8);

    if (d == 0) {
        float ce = -(0.2f / 8.f) * slp - 0.8f * kg;
        float wgt = fminf(dist[pix], 20.f) / 20.f;
        cearr[pix] = ce * wgt;
    }
}

// ---------------------------------------------------------------------------
// Stage 7a: block-tree reduce of dense cearr (1024 floats/block, fixed order).
// ---------------------------------------------------------------------------
__global__ __launch_bounds__(256) void redA_kernel(const float4* __restrict__ cearr4,
                                                   float* __restrict__ partials) {
    __shared__ float r[256];
    const int tid = threadIdx.x;
    float4 v = cearr4[(size_t)blockIdx.x * 256 + tid];
    r[tid] = (v.x + v.y) + (v.z + v.w);
    __syncthreads();
    for (int s = 128; s > 0; s >>= 1) {
        if (tid < s) r[tid] += r[tid + s];
        __syncthreads();
    }
    if (tid == 0) partials[blockIdx.x] = r[0];
}

// ---------------------------------------------------------------------------
// Stage 7b: final: sum partials + valid count -> loss.
// ---------------------------------------------------------------------------
__global__ __launch_bounds__(256) void redB_kernel(const float* __restrict__ partials,
                                                   const unsigned int* __restrict__ cnts,
                                                   float* __restrict__ out) {
    __shared__ float r[256];
    const int tid = threadIdx.x;
    r[tid] = partials[tid] + partials[tid + 256] + partials[tid + 512] + partials[tid + 768];
    __syncthreads();
    for (int s = 128; s > 0; s >>= 1) {
        if (tid < s) r[tid] += r[tid + s];
        __syncthreads();
    }
    if (tid == 0) {
        unsigned int vf = 0;
        for (int q = 0; q < NSEG; ++q) vf += cnts[q];
        out[0] = r[0] / fmaxf((float)vf, 1.f);
    }
}

extern "C" void kernel_launch(void* const* d_in, const int* in_sizes, int n_in,
                              void* d_out, int out_size, void* d_ws, size_t ws_size,
                              hipStream_t stream) {
    const float* logits = (const float*)d_in[0];
    const int* target = (const int*)d_in[1];
    float* out = (float*)d_out;

    float* fws = (float*)d_ws;
    float* distb = fws;                         // NPIX floats
    float* klb = fws + NPIX;                    // NPIX floats
    float* lsem = fws + 2 * (size_t)NPIX;       // NPIX floats
    float* cearr = fws + 3 * (size_t)NPIX;      // NPIX floats (own region: no alias)
    unsigned int* hist = (unsigned int*)(fws + 4 * (size_t)NPIX);   // NREP*HSTRIDE
    unsigned int* flags = hist + NREP * HSTRIDE;                    // NB
    unsigned int* cnts = flags + NB;                                // NSEG
    float* epsb = (float*)(cnts + NSEG);                            // 1 (+pad)
    unsigned int* list = (unsigned int*)(epsb + 64);                // NSEG*SEGCAP
    float* partials = (float*)(list + NSEG * SEGCAP);               // 1024
    unsigned int* maskw = (unsigned int*)(partials + 1024);         // NB*NWRD*NW

    // zero histogram + flags + segment counters (tiny, one fill dispatch)
    hipMemsetAsync(hist, 0, (NREP * HSTRIDE + NB + NSEG) * sizeof(unsigned int), stream);

    bound_kernel<<<NB * NWRD * NW / 64, 64, 0, stream>>>(target, maskw, flags);
    vdist_kernel<<<(NPIX + 255) / 256, 256, 0, stream>>>(maskw, distb);
    rowmin_kernel<<<NB * NH, 256, 0, stream>>>(distb, flags);

    lse_kernel<<<NPIX / 256, 256, 0, stream>>>(logits, lsem, cearr);
    klhist_kernel<<<NB * NH * 2, 256, 0, stream>>>(logits, lsem, klb, hist);
    eps_kernel<<<1, 256, 0, stream>>>(hist, epsb);

    dim3 tiles(NW / TS, NH / TS, NB);
    valid_kernel<<<tiles, 256, 0, stream>>>(klb, distb, epsb, cnts, list);
    dirce_kernel<<<NSEG * SEGCAP * 8 / 256, 256, 0, stream>>>(logits, lsem, distb,
                                                              cnts, list, cearr);
    redA_kernel<<<1024, 256, 0, stream>>>((const float4*)cearr, partials);
    redB_kernel<<<1, 256, 0, stream>>>(partials, cnts, out);
}

// Round 7
// 121.657 us; speedup vs baseline: 5.0206x; 1.0618x over previous
//
#include <hip/hip_runtime.h>
#include <math.h>

#define NB 4
#define NH 512
#define NW 512
#define NC 19
#define NPIX (NB*NH*NW)
#define TS 16
#define NLAD 128
#define INF6 1.0e6f
#define MAXDIS 1.0e5f
#define NWRD 16          // 512 rows / 32 bits
#define NREP 8           // histogram replicas
#define HSTRIDE 132      // padded per-replica stride (129 bins)
#define NSEG 128         // compaction segments
#define SEGCAP 512       // entries per segment (expected max ~250)
#define NZERO (NREP*HSTRIDE + NB + NSEG)   // words zeroed by lse block 0

// ---------------------------------------------------------------------------
// Stage 0+3a: per-pixel log-sum-exp map (float4-staged to LDS, reg reduce).
// Runs FIRST. Block 0 also zeroes hist+flags+cnts (replaces the 46us
// fixed-cost rocclr fillBuffer dispatch); stream order guarantees
// completion before any consumer kernel launches. Also zero-fills cearr.
// ---------------------------------------------------------------------------
__global__ __launch_bounds__(256) void lse_kernel(const float* __restrict__ logits,
                                                  float* __restrict__ lsem,
                                                  float* __restrict__ cearr,
                                                  unsigned int* __restrict__ zbuf) {
    __shared__ float4 S4[1216];                 // 256*19 floats
    const int tid = threadIdx.x;
    const size_t pix0 = (size_t)blockIdx.x * 256;
    const float4* src = reinterpret_cast<const float4*>(logits + pix0 * NC);
#pragma unroll
    for (int t = 0; t < 5; ++t) {
        int idx = tid + t * 256;
        if (idx < 1216) S4[idx] = src[idx];
    }
    cearr[pix0 + tid] = 0.f;
    if (blockIdx.x == 0) {
        for (int k = tid; k < NZERO; k += 256) zbuf[k] = 0u;
    }
    __syncthreads();
    const float* L = (const float*)S4;
    const float* v = &L[tid * NC];
    float mx = v[0];
#pragma unroll
    for (int c = 1; c < NC; ++c) mx = fmaxf(mx, v[c]);
    float se = 0.f;
#pragma unroll
    for (int c = 0; c < NC; ++c) se += expf(v[c] - mx);
    lsem[pix0 + tid] = mx + logf(se);
}

// ---------------------------------------------------------------------------
// Stage 1a: boundary bitmasks. One thread per (b, word, column).
// ---------------------------------------------------------------------------
__global__ __launch_bounds__(64) void bound_kernel(const int* __restrict__ tgt,
                                                   unsigned int* __restrict__ maskw,
                                                   unsigned int* __restrict__ flags) {
    int cidx = blockIdx.x * 64 + threadIdx.x;           // [b][w][j]
    int j = cidx & (NW - 1);
    int w = (cidx >> 9) & (NWRD - 1);
    int b = cidx >> 13;
    if (b >= NB) return;
    const int* t = tgt + (size_t)b * NH * NW;
    unsigned int mask = 0u;
    int i0 = w * 32;
    int cur = t[(size_t)i0 * NW + j];
    for (int k = 0; k < 32; ++k) {
        int i = i0 + k;
        int nxt = (i + 1 < NH) ? t[(size_t)(i + 1) * NW + j] : cur;
        bool bnd = (cur == 255);
        if (i + 1 < NH && nxt != cur) bnd = true;
        if (j + 1 < NW && t[(size_t)i * NW + j + 1] != cur) bnd = true;
        if (bnd) mask |= (1u << k);
        cur = nxt;
    }
    maskw[cidx] = mask;
    if (__any(mask != 0u) && (threadIdx.x & 63) == 0)
        atomicOr(&flags[b], 1u);
}

// ---------------------------------------------------------------------------
// Stage 1b: vertical distance via nearest-set-bit. One thread per pixel.
// ---------------------------------------------------------------------------
__global__ __launch_bounds__(256) void vdist_kernel(const unsigned int* __restrict__ maskw,
                                                    float* __restrict__ g2) {
    int pix = blockIdx.x * 256 + threadIdx.x;
    if (pix >= NPIX) return;
    int b = pix >> 18;
    int rem = pix & (NH * NW - 1);
    int i = rem >> 9;
    int j = rem & (NW - 1);
    const unsigned int* mcol = maskw + (size_t)b * NWRD * NW;
    int wi = i >> 5, bi = i & 31;

    int down = 1 << 20;
    unsigned int m = mcol[(size_t)wi * NW + j] & ((2u << bi) - 1u);
    if (m) down = bi - (31 - __clz(m));
    else {
        for (int w = wi - 1; w >= 0; --w) {
            unsigned int mm = mcol[(size_t)w * NW + j];
            if (mm) { down = bi + 32 * (wi - w) - (31 - __clz(mm)); break; }
        }
    }
    int up = 1 << 20;
    unsigned int mu = mcol[(size_t)wi * NW + j] & ~((1u << bi) - 1u);
    if (mu) up = (__ffs(mu) - 1) - bi;
    else {
        for (int w = wi + 1; w < NWRD; ++w) {
            unsigned int mm = mcol[(size_t)w * NW + j];
            if (mm) { up = 32 * (w - wi) + (__ffs(mm) - 1) - bi; break; }
        }
    }
    int gi = min(down, up);
    float G = (gi >= (1 << 20)) ? INF6 : (float)gi;
    g2[pix] = G * G;
}

// ---------------------------------------------------------------------------
// Stage 2: row-wise min-plus transform -> final distance map (in place).
// ---------------------------------------------------------------------------
__global__ __launch_bounds__(256) void rowmin_kernel(float* __restrict__ g2,
                                                     const unsigned int* __restrict__ flags) {
    int row = blockIdx.x;              // b*NH + i
    int b = row / NH;
    float* g = g2 + (size_t)row * NW;
    __shared__ float s[NW];
    for (int j = threadIdx.x; j < NW; j += blockDim.x) s[j] = g[j];
    __syncthreads();
    bool has = flags[b] != 0u;
    for (int j = threadIdx.x; j < NW; j += blockDim.x) {
        float best = s[j];
        for (int r = 1; r < NW; ++r) {
            float rr = (float)(r * r);
            if (rr >= best) break;
            int jl = j - r, jr = j + r;
            if (jl >= 0) best = fminf(best, s[jl] + rr);
            if (jr < NW) best = fminf(best, s[jr] + rr);
        }
        g[j] = has ? fmaxf(sqrtf(best) - 1.f, 0.f) : 0.f;
    }
}

// ---------------------------------------------------------------------------
// Stage 3b: kl map + fused 8-replica histogram.
// ---------------------------------------------------------------------------
__global__ __launch_bounds__(256) void klhist_kernel(const float* __restrict__ logits,
                                                     const float* __restrict__ lsem,
                                                     float* __restrict__ klb,
                                                     unsigned int* __restrict__ hist) {
    __shared__ float4 Lc4[1221];
    __shared__ float4 Ld4[1216];
    __shared__ float lad[NLAD];
    __shared__ unsigned int lh[NLAD + 1];
    const int tid = threadIdx.x;
    const int cid = blockIdx.x;
    const int j0 = (cid & 1) * 256;
    const int i = (cid >> 1) & (NH - 1);
    const int b = cid >> 10;

    if (tid == 0) {
        float e = 1e-5f;
        for (int k = 0; k < NLAD; ++k) { lad[k] = e; e *= 1.2f; }
    }
    if (tid < NLAD + 1) lh[tid] = 0u;

    const size_t rowpix = (size_t)(b * NH + i) * NW + j0;
    const float4* src = reinterpret_cast<const float4*>(logits + rowpix * NC);
    const int n4c = (j0 == 0) ? 1221 : 1216;
#pragma unroll
    for (int t = 0; t < 5; ++t) {
        int idx = tid + t * 256;
        if (idx < n4c) Lc4[idx] = src[idx];
    }
    if (i < NH - 1) {
        const float4* srcd = reinterpret_cast<const float4*>(logits + (rowpix + NW) * NC);
#pragma unroll
        for (int t = 0; t < 5; ++t) {
            int idx = tid + t * 256;
            if (idx < 1216) Ld4[idx] = srcd[idx];
        }
    }
    __syncthreads();

    const float* Lc = (const float*)Lc4;
    const float* Ld = (const float*)Ld4;
    const int j = j0 + tid;
    const size_t pix = rowpix + tid;
    const float lse_c = lsem[pix];
    const float lse_r = (j < NW - 1) ? lsem[pix + 1] : 0.f;
    const float lse_d = (i < NH - 1) ? lsem[pix + NW] : 0.f;

    const float* lc = &Lc[tid * NC];
    const float* lr = &Lc[(tid + 1) * NC];
    const float* ld = &Ld[tid * NC];
    float negH = 0.f, dotr = 0.f, dotd = 0.f;
#pragma unroll
    for (int c = 0; c < NC; ++c) {
        float s = lc[c] - lse_c;
        float p = expf(s);
        negH += p * s;
        dotr += p * lr[c];
        dotd += p * ld[c];
    }
    float kl = 0.f;
    if (i < NH - 1) kl += negH + lse_d - dotd;
    if (j < NW - 1) kl += negH + lse_r - dotr;
    klb[pix] = kl;

    int lo = 0, hi = NLAD;
    while (lo < hi) { int mid = (lo + hi) >> 1; if (kl > lad[mid]) lo = mid + 1; else hi = mid; }
    atomicAdd(&lh[lo], 1u);
    __syncthreads();
    if (tid < NLAD + 1 && lh[tid])
        atomicAdd(&hist[(cid & (NREP - 1)) * HSTRIDE + tid], lh[tid]);
}

// ---------------------------------------------------------------------------
// Stage 5: eps selection (exact while-loop replication).
// ---------------------------------------------------------------------------
__global__ void eps_kernel(const unsigned int* __restrict__ hist, float* __restrict__ epsout) {
    __shared__ unsigned int tot[NLAD + 1];
    int k = threadIdx.x;
    if (k < NLAD + 1) {
        unsigned int s = 0;
        for (int r = 0; r < NREP; ++r) s += hist[r * HSTRIDE + k];
        tot[k] = s;
    }
    __syncthreads();
    if (k == 0) {
        float lad[NLAD];
        float e = 1e-5f;
        for (int q = 0; q < NLAD; ++q) { lad[q] = e; e *= 1.2f; }
        unsigned int suf[NLAD + 2];
        suf[NLAD + 1] = 0u;
        for (int q = NLAD; q >= 0; --q) suf[q] = suf[q + 1] + tot[q];
        int K = 0;
        while (K < NLAD - 1 && (float)suf[K + 1] > 2621.44f) K++;
        epsout[0] = lad[K];
    }
}

// ---------------------------------------------------------------------------
// Stage 6a: validity pass (dilation + argmin only) + wave-ballot compaction.
// ---------------------------------------------------------------------------
__global__ __launch_bounds__(256) void valid_kernel(const float* __restrict__ klb,
                                                    const float* __restrict__ dist,
                                                    const float* __restrict__ epsp,
                                                    unsigned int* __restrict__ cnts,
                                                    unsigned int* __restrict__ list) {
    const int tid = threadIdx.x;
    const int b = blockIdx.z;
    const int i = blockIdx.y * TS + (tid >> 4);
    const int j = blockIdx.x * TS + (tid & 15);
    const float eps = epsp[0];
    const float* klp = klb + (size_t)b * NH * NW;
    const float* dp = dist + (size_t)b * NH * NW;

    bool pb = false;
    for (int di = -1; di <= 1; ++di) {
        int ii = i + di; if (ii < 0 || ii >= NH) continue;
        for (int dj = -1; dj <= 1; ++dj) {
            int jj = j + dj; if (jj < 0 || jj >= NW) continue;
            if (klp[(size_t)ii * NW + jj] > eps) pb = true;
        }
    }

    const int dxs[9] = {1, -1, 0, 0, -1, 1, -1, 1, 0};
    const int dys[9] = {0, 0, -1, 1, 1, 1, -1, -1, 0};
    float best = MAXDIS; int gidx = 0;
#pragma unroll
    for (int k = 0; k < 9; ++k) {
        int ii = i + dxs[k], jj = j + dys[k];
        float v = (ii >= 0 && ii < NH && jj >= 0 && jj < NW) ? dp[(size_t)ii * NW + jj] : MAXDIS;
        if (k == 0) { best = v; gidx = 0; }
        else if (v < best) { best = v; gidx = k; }
    }
    bool valid = pb && (gidx != 8);

    const int pix = (b * NH + i) * NW + j;
    const int lane = tid & 63;
    unsigned long long mk = __ballot(valid);
    int cnt = __popcll(mk);
    int flatw = (((blockIdx.z * gridDim.y + blockIdx.y) * gridDim.x + blockIdx.x) << 2) | (tid >> 6);
    int seg = flatw & (NSEG - 1);
    unsigned int base = 0u;
    if (lane == 0 && cnt) base = atomicAdd(&cnts[seg], (unsigned int)cnt);
    base = (unsigned int)__shfl((int)base, 0, 64);
    if (valid) {
        unsigned int off = base + (unsigned int)__popcll(mk & ((1ull << lane) - 1ull));
        if (off < SEGCAP)
            list[seg * SEGCAP + off] = (unsigned int)pix | ((unsigned int)gidx << 20);
    }
}

// ---------------------------------------------------------------------------
// Stage 6b: CE over valid pixels only. 8 lanes per pixel (one per neighbor).
// ---------------------------------------------------------------------------
__global__ __launch_bounds__(256) void dirce_kernel(const float* __restrict__ logits,
                                                    const float* __restrict__ lsem,
                                                    const float* __restrict__ dist,
                                                    const unsigned int* __restrict__ cnts,
                                                    const unsigned int* __restrict__ list,
                                                    float* __restrict__ cearr) {
    const int t = blockIdx.x * 256 + threadIdx.x;
    const int e = t >> 3;                       // entry
    const int d = t & 7;                        // neighbor lane
    const int s = e >> 9;                       // segment (SEGCAP=512)
    const int k = e & (SEGCAP - 1);
    unsigned int cs = cnts[s];
    if ((unsigned int)k >= min(cs, (unsigned int)SEGCAP)) return;
    unsigned int w = list[s * SEGCAP + k];
    const int pix = (int)(w & (NPIX - 1));
    const int gidx = (int)(w >> 20);
    const int j = pix & (NW - 1);
    const int i = (pix >> 9) & (NH - 1);

    const unsigned int DXP = (2u<<0)|(0u<<2)|(1u<<4)|(1u<<6)|(0u<<8)|(2u<<10)|(0u<<12)|(2u<<14);
    const unsigned int DYP = (1u<<0)|(1u<<2)|(0u<<4)|(2u<<6)|(2u<<8)|(2u<<10)|(0u<<12)|(0u<<14);
    const int dx = (int)((DXP >> (2 * d)) & 3u) - 1;
    const int dy = (int)((DYP >> (2 * d)) & 3u) - 1;
    const int ii = i + dx, jj = j + dy;
    const bool inb = (ii >= 0 && ii < NH && jj >= 0 && jj < NW);

    const float lse_c = lsem[pix];
    const float* lcp = logits + (size_t)pix * NC;
    float lc[NC];
    float sumlc = 0.f;
#pragma unroll
    for (int c = 0; c < NC; ++c) { lc[c] = lcp[c]; sumlc += lc[c]; }

    float klm;
    if (inb) {
        const int npix = pix + dx * NW + dy;
        const float lse_n = lsem[npix];
        const float* lnp = logits + (size_t)npix * NC;
        float negH = 0.f, dot = 0.f;
#pragma unroll
        for (int c = 0; c < NC; ++c) {
            float sv = lnp[c] - lse_n;
            float p = expf(sv);
            negH += p * sv;
            dot += p * lc[c];
        }
        klm = negH + lse_c - dot;
    } else {
        klm = -logf(19.f) + lse_c - sumlc / 19.f;
    }

    float m2 = klm;
#pragma unroll
    for (int o = 4; o > 0; o >>= 1) m2 = fmaxf(m2, __shfl_xor(m2, o, 8));
    float ex = expf(klm - m2);
    float s2 = ex;
#pragma unroll
    for (int o = 4; o > 0; o >>= 1) s2 += __shfl_xor(s2, o, 8);
    float lse = m2 + logf(s2);
    float lp = klm - lse;
    float slp = lp;
#pragma unroll
    for (int o = 4; o > 0; o >>= 1) slp += __shfl_xor(slp, o, 8);
    float kg = (d == gidx) ? lp : 0.f;
#pragma unroll
    for (int o = 4; o > 0; o >>= 1) kg += __shfl_xor(kg, o, 8);

    if (d == 0) {
        float ce = -(0.2f / 8.f) * slp - 0.8f * kg;
        float wgt = fminf(dist[pix], 20.f) / 20.f;
        cearr[pix] = ce * wgt;
    }
}

// ---------------------------------------------------------------------------
// Stage 7a: block-tree reduce of dense cearr (1024 floats/block, fixed order).
// ---------------------------------------------------------------------------
__global__ __launch_bounds__(256) void redA_kernel(const float4* __restrict__ cearr4,
                                                   float* __restrict__ partials) {
    __shared__ float r[256];
    const int tid = threadIdx.x;
    float4 v = cearr4[(size_t)blockIdx.x * 256 + tid];
    r[tid] = (v.x + v.y) + (v.z + v.w);
    __syncthreads();
    for (int s = 128; s > 0; s >>= 1) {
        if (tid < s) r[tid] += r[tid + s];
        __syncthreads();
    }
    if (tid == 0) partials[blockIdx.x] = r[0];
}

// ---------------------------------------------------------------------------
// Stage 7b: final: sum partials + valid count -> loss.
// ---------------------------------------------------------------------------
__global__ __launch_bounds__(256) void redB_kernel(const float* __restrict__ partials,
                                                   const unsigned int* __restrict__ cnts,
                                                   float* __restrict__ out) {
    __shared__ float r[256];
    const int tid = threadIdx.x;
    r[tid] = partials[tid] + partials[tid + 256] + partials[tid + 512] + partials[tid + 768];
    __syncthreads();
    for (int s = 128; s > 0; s >>= 1) {
        if (tid < s) r[tid] += r[tid + s];
        __syncthreads();
    }
    if (tid == 0) {
        unsigned int vf = 0;
        for (int q = 0; q < NSEG; ++q) vf += cnts[q];
        out[0] = r[0] / fmaxf((float)vf, 1.f);
    }
}

extern "C" void kernel_launch(void* const* d_in, const int* in_sizes, int n_in,
                              void* d_out, int out_size, void* d_ws, size_t ws_size,
                              hipStream_t stream) {
    const float* logits = (const float*)d_in[0];
    const int* target = (const int*)d_in[1];
    float* out = (float*)d_out;

    float* fws = (float*)d_ws;
    float* distb = fws;                         // NPIX floats
    float* klb = fws + NPIX;                    // NPIX floats
    float* lsem = fws + 2 * (size_t)NPIX;       // NPIX floats
    float* cearr = fws + 3 * (size_t)NPIX;      // NPIX floats
    unsigned int* hist = (unsigned int*)(fws + 4 * (size_t)NPIX);   // NREP*HSTRIDE
    unsigned int* flags = hist + NREP * HSTRIDE;                    // NB
    unsigned int* cnts = flags + NB;                                // NSEG
    float* epsb = (float*)(cnts + NSEG);                            // 1 (+pad)
    unsigned int* list = (unsigned int*)(epsb + 64);                // NSEG*SEGCAP
    float* partials = (float*)(list + NSEG * SEGCAP);               // 1024
    unsigned int* maskw = (unsigned int*)(partials + 1024);         // NB*NWRD*NW

    // lse runs first: block 0 zeroes hist+flags+cnts (contiguous at `hist`),
    // stream order makes them ready before bound/klhist/valid consume them.
    lse_kernel<<<NPIX / 256, 256, 0, stream>>>(logits, lsem, cearr, hist);

    bound_kernel<<<NB * NWRD * NW / 64, 64, 0, stream>>>(target, maskw, flags);
    vdist_kernel<<<(NPIX + 255) / 256, 256, 0, stream>>>(maskw, distb);
    rowmin_kernel<<<NB * NH, 256, 0, stream>>>(distb, flags);

    klhist_kernel<<<NB * NH * 2, 256, 0, stream>>>(logits, lsem, klb, hist);
    eps_kernel<<<1, 256, 0, stream>>>(hist, epsb);

    dim3 tiles(NW / TS, NH / TS, NB);
    valid_kernel<<<tiles, 256, 0, stream>>>(klb, distb, epsb, cnts, list);
    dirce_kernel<<<NSEG * SEGCAP * 8 / 256, 256, 0, stream>>>(logits, lsem, distb,
                                                              cnts, list, cearr);
    redA_kernel<<<1024, 256, 0, stream>>>((const float4*)cearr, partials);
    redB_kernel<<<1, 256, 0, stream>>>(partials, cnts, out);
}